// Round 1
// baseline (3140.590 us; speedup 1.0000x reference)
//
#include <hip/hip_runtime.h>

namespace {
constexpr int kN = 100000;   // nodes
constexpr int kD = 128;      // feature dim
constexpr int kR = 3;        // relations
constexpr int kE = 500000;   // edges per relation
constexpr int kB = 2;        // bases
}

// ---------------- degree counting ----------------
__global__ __launch_bounds__(256)
void count_deg_kernel(const int* __restrict__ dst, unsigned* __restrict__ cnt)
{
    int i = blockIdx.x * 256 + threadIdx.x;
    if (i < kR * kE) {
        int r = i / kE;
        atomicAdd(&cnt[r * kN + dst[i]], 1u);
    }
}

__global__ __launch_bounds__(256)
void invdeg_kernel(const unsigned* __restrict__ cnt, float* __restrict__ inv)
{
    int i = blockIdx.x * 256 + threadIdx.x;
    if (i < kR * kN) {
        unsigned c = cnt[i];
        inv[i] = 1.0f / (float)(c > 1u ? c : 1u);
    }
}

// ---------------- W_r = sum_b coeff[r,b] * basis[b] ----------------
__global__ __launch_bounds__(256)
void wbuild_kernel(const float* __restrict__ basis, const float* __restrict__ coeff,
                   float* __restrict__ W)
{
    int i = blockIdx.x * 256 + threadIdx.x;
    if (i < kR * kD * kD) {
        int r = i / (kD * kD);
        int m = i - r * kD * kD;
        W[i] = coeff[r * kB] * basis[m] + coeff[r * kB + 1] * basis[kD * kD + m];
    }
}

// ---------------- C[M,128] = op(A)[M,128] @ W[128,128] (+ bias) ----------------
// 256 threads, BM=128, BN=128, BK=16; 8x8 accumulators per thread.
template<bool RELUA, bool HASBIAS>
__global__ __launch_bounds__(256)
void gemm128_kernel(const float* __restrict__ A, const float* __restrict__ W,
                    const float* __restrict__ bias, float* __restrict__ C, int M)
{
    __shared__ float As[16 * 128];   // As[k][m] (transposed)
    __shared__ float Bs[16 * 128];   // Bs[k][o]
    const int tid = threadIdx.x;
    const int bm = blockIdx.x * 128;

    const int ty = tid >> 4;          // 0..15: output row group / staging k-row
    const int tx = tid & 15;          // 0..15: output col group / staging segment
    const int lrow = tid >> 1;        // 0..127: A staging row
    const int lk = (tid & 1) * 8;     // 0 or 8: A staging k-offset
    const int grow = bm + lrow;

    float acc[8][8];
    #pragma unroll
    for (int i = 0; i < 8; ++i)
        #pragma unroll
        for (int j = 0; j < 8; ++j) acc[i][j] = 0.0f;

    for (int kt = 0; kt < 8; ++kt) {
        float4 a0 = make_float4(0.f, 0.f, 0.f, 0.f);
        float4 a1 = make_float4(0.f, 0.f, 0.f, 0.f);
        if (grow < M) {
            const float* ap = A + (size_t)grow * kD + kt * 16 + lk;
            a0 = *(const float4*)ap;
            a1 = *(const float4*)(ap + 4);
        }
        if (RELUA) {
            a0.x = fmaxf(a0.x, 0.f); a0.y = fmaxf(a0.y, 0.f);
            a0.z = fmaxf(a0.z, 0.f); a0.w = fmaxf(a0.w, 0.f);
            a1.x = fmaxf(a1.x, 0.f); a1.y = fmaxf(a1.y, 0.f);
            a1.z = fmaxf(a1.z, 0.f); a1.w = fmaxf(a1.w, 0.f);
        }
        const float* wp = W + (size_t)(kt * 16 + ty) * kD + tx * 8;
        const float4 b0 = *(const float4*)wp;
        const float4 b1 = *(const float4*)(wp + 4);

        __syncthreads();   // previous iteration's compute done reading As/Bs
        As[(lk + 0) * 128 + lrow] = a0.x;
        As[(lk + 1) * 128 + lrow] = a0.y;
        As[(lk + 2) * 128 + lrow] = a0.z;
        As[(lk + 3) * 128 + lrow] = a0.w;
        As[(lk + 4) * 128 + lrow] = a1.x;
        As[(lk + 5) * 128 + lrow] = a1.y;
        As[(lk + 6) * 128 + lrow] = a1.z;
        As[(lk + 7) * 128 + lrow] = a1.w;
        *(float4*)&Bs[ty * 128 + tx * 8]     = b0;
        *(float4*)&Bs[ty * 128 + tx * 8 + 4] = b1;
        __syncthreads();

        #pragma unroll
        for (int kk = 0; kk < 16; ++kk) {
            const float4 av0 = *(const float4*)&As[kk * 128 + ty * 8];
            const float4 av1 = *(const float4*)&As[kk * 128 + ty * 8 + 4];
            const float4 bv0 = *(const float4*)&Bs[kk * 128 + tx * 8];
            const float4 bv1 = *(const float4*)&Bs[kk * 128 + tx * 8 + 4];
            const float a[8] = {av0.x, av0.y, av0.z, av0.w, av1.x, av1.y, av1.z, av1.w};
            const float b[8] = {bv0.x, bv0.y, bv0.z, bv0.w, bv1.x, bv1.y, bv1.z, bv1.w};
            #pragma unroll
            for (int i = 0; i < 8; ++i)
                #pragma unroll
                for (int j = 0; j < 8; ++j)
                    acc[i][j] = fmaf(a[i], b[j], acc[i][j]);
        }
    }

    float bb[8];
    #pragma unroll
    for (int j = 0; j < 8; ++j) bb[j] = HASBIAS ? bias[tx * 8 + j] : 0.0f;

    #pragma unroll
    for (int i = 0; i < 8; ++i) {
        const int row = bm + ty * 8 + i;
        if (row < M) {
            float4 o0, o1;
            o0.x = acc[i][0] + bb[0]; o0.y = acc[i][1] + bb[1];
            o0.z = acc[i][2] + bb[2]; o0.w = acc[i][3] + bb[3];
            o1.x = acc[i][4] + bb[4]; o1.y = acc[i][5] + bb[5];
            o1.z = acc[i][6] + bb[6]; o1.w = acc[i][7] + bb[7];
            float* cp = C + (size_t)row * kD + tx * 8;
            *(float4*)cp       = o0;
            *(float4*)(cp + 4) = o1;
        }
    }
}

// ---------------- edge scatter: g[dst] += t[src] * invdeg[dst] ----------------
// one wave (64 lanes) per edge; 2 floats per lane.
__global__ __launch_bounds__(256)
void scatter_kernel(const float* __restrict__ t, const int* __restrict__ src,
                    const int* __restrict__ dst, const float* __restrict__ invdeg,
                    float* __restrict__ g)
{
    const int lane = threadIdx.x & 63;
    const int e = blockIdx.x * 4 + (threadIdx.x >> 6);
    if (e >= kE) return;
    const int s = src[e];
    const int d = dst[e];
    const float w = invdeg[d];
    const float2 v = *(const float2*)(t + (size_t)s * kD + lane * 2);
    float* gp = g + (size_t)d * kD + lane * 2;
    atomicAdd(gp,     v.x * w);
    atomicAdd(gp + 1, v.y * w);
}

// ---------------- final relu copy ----------------
__global__ __launch_bounds__(256)
void relu_kernel(const float* __restrict__ in, float* __restrict__ out)
{
    const int i = blockIdx.x * 256 + threadIdx.x;   // over N*D/4 exactly
    const float4 v = ((const float4*)in)[i];
    float4 o;
    o.x = fmaxf(v.x, 0.f); o.y = fmaxf(v.y, 0.f);
    o.z = fmaxf(v.z, 0.f); o.w = fmaxf(v.w, 0.f);
    ((float4*)out)[i] = o;
}

extern "C" void kernel_launch(void* const* d_in, const int* in_sizes, int n_in,
                              void* d_out, int out_size, void* d_ws, size_t ws_size,
                              hipStream_t stream)
{
    const float* x      = (const float*)d_in[0];
    const int*   esrc   = (const int*)d_in[1];
    const int*   edst   = (const int*)d_in[2];
    const float* proj_w = (const float*)d_in[3];
    const float* proj_b = (const float*)d_in[4];
    const float* basis1 = (const float*)d_in[5];
    const float* coeff1 = (const float*)d_in[6];
    const float* bias1  = (const float*)d_in[7];
    const float* loop1  = (const float*)d_in[8];
    const float* basis2 = (const float*)d_in[9];
    const float* coeff2 = (const float*)d_in[10];
    const float* bias2  = (const float*)d_in[11];
    const float* loop2  = (const float*)d_in[12];

    // workspace layout (floats)
    float* ws = (float*)d_ws;
    float* h    = ws;                                  // N*D (proj out; later reused as g2)
    float* t    = h + (size_t)kN * kD;                 // N*D (per-relation transform)
    float* W1   = t + (size_t)kN * kD;                 // R*D*D
    float* W2   = W1 + (size_t)kR * kD * kD;           // R*D*D
    float* invd = W2 + (size_t)kR * kD * kD;           // R*N
    unsigned* cnt = (unsigned*)(invd + (size_t)kR * kN); // R*N
    float* g1 = (float*)d_out;                         // layer-1 pre-relu accumulator

    // ---- edge structure (shared by both layers) ----
    hipMemsetAsync(cnt, 0, sizeof(unsigned) * (size_t)kR * kN, stream);
    count_deg_kernel<<<(kR * kE + 255) / 256, 256, 0, stream>>>(edst, cnt);
    invdeg_kernel<<<(kR * kN + 255) / 256, 256, 0, stream>>>(cnt, invd);
    wbuild_kernel<<<(kR * kD * kD + 255) / 256, 256, 0, stream>>>(basis1, coeff1, W1);
    wbuild_kernel<<<(kR * kD * kD + 255) / 256, 256, 0, stream>>>(basis2, coeff2, W2);

    const int gblocks = (kN + 127) / 128;

    // ---- projection: h = x @ proj_w + proj_b ----
    gemm128_kernel<false, true><<<gblocks, 256, 0, stream>>>(x, proj_w, proj_b, h, kN);

    // ---- layer 1: g1 = h@loop1 + bias1 + sum_r scatter(h@W1_r) ----
    gemm128_kernel<false, true><<<gblocks, 256, 0, stream>>>(h, loop1, bias1, g1, kN);
    for (int r = 0; r < kR; ++r) {
        gemm128_kernel<false, false><<<gblocks, 256, 0, stream>>>(
            h, W1 + (size_t)r * kD * kD, nullptr, t, kN);
        scatter_kernel<<<(kE + 3) / 4, 256, 0, stream>>>(
            t, esrc + (size_t)r * kE, edst + (size_t)r * kE, invd + (size_t)r * kN, g1);
    }

    // ---- layer 2: input = relu(g1) applied on read; g2 reuses h buffer ----
    float* g2 = h;
    gemm128_kernel<true, true><<<gblocks, 256, 0, stream>>>(g1, loop2, bias2, g2, kN);
    for (int r = 0; r < kR; ++r) {
        gemm128_kernel<true, false><<<gblocks, 256, 0, stream>>>(
            g1, W2 + (size_t)r * kD * kD, nullptr, t, kN);
        scatter_kernel<<<(kE + 3) / 4, 256, 0, stream>>>(
            t, esrc + (size_t)r * kE, edst + (size_t)r * kE, invd + (size_t)r * kN, g2);
    }

    // ---- final: d_out = relu(g2) ----
    relu_kernel<<<(kN * kD / 4) / 256, 256, 0, stream>>>(g2, (float*)d_out);
}

// Round 2
// 1136.639 us; speedup vs baseline: 2.7631x; 2.7631x over previous
//
#include <hip/hip_runtime.h>

namespace {
constexpr int kN = 100000;   // nodes
constexpr int kD = 128;      // feature dim
constexpr int kR = 3;        // relations
constexpr int kE = 500000;   // edges per relation
constexpr int kB = 2;        // bases
constexpr int kRN = kR * kN;          // 300000 segments
constexpr int kRE = kR * kE;          // 1500000 edges
constexpr int kNB = (kRN + 1023) / 1024;  // scan blocks (293)
}

// ---------------- degree counting ----------------
__global__ __launch_bounds__(256)
void count_deg_kernel(const int* __restrict__ dst, unsigned* __restrict__ cnt)
{
    int i = blockIdx.x * 256 + threadIdx.x;
    if (i < kRE) {
        int r = i / kE;
        atomicAdd(&cnt[r * kN + dst[i]], 1u);
    }
}

__global__ __launch_bounds__(256)
void invdeg_kernel(const unsigned* __restrict__ cnt, float* __restrict__ inv)
{
    int i = blockIdx.x * 256 + threadIdx.x;
    if (i < kRN) {
        unsigned c = cnt[i];
        inv[i] = 1.0f / (float)(c > 1u ? c : 1u);
    }
}

// ---------------- exclusive scan of cnt -> rowptr (3 kernels) ----------------
__global__ __launch_bounds__(256)
void scan_block_kernel(const unsigned* __restrict__ cnt, unsigned* __restrict__ part,
                       unsigned* __restrict__ blksum)
{
    __shared__ unsigned s[256];
    const int tid = threadIdx.x;
    const int base = blockIdx.x * 1024 + tid * 4;
    unsigned v[4], sum = 0;
    #pragma unroll
    for (int j = 0; j < 4; ++j) {
        v[j] = (base + j < kRN) ? cnt[base + j] : 0u;
        sum += v[j];
    }
    s[tid] = sum;
    __syncthreads();
    #pragma unroll
    for (int off = 1; off < 256; off <<= 1) {
        unsigned t = (tid >= off) ? s[tid - off] : 0u;
        __syncthreads();
        s[tid] += t;
        __syncthreads();
    }
    unsigned run = s[tid] - sum;  // exclusive prefix of this thread's chunk
    if (tid == 255) blksum[blockIdx.x] = s[255];
    #pragma unroll
    for (int j = 0; j < 4; ++j) {
        if (base + j < kRN) part[base + j] = run;
        run += v[j];
    }
}

__global__ void scan_tops_kernel(unsigned* __restrict__ blksum)
{
    if (threadIdx.x == 0 && blockIdx.x == 0) {
        unsigned run = 0;
        for (int i = 0; i < kNB; ++i) {
            unsigned t = blksum[i];
            blksum[i] = run;
            run += t;
        }
    }
}

__global__ __launch_bounds__(256)
void scan_add_kernel(const unsigned* __restrict__ part, const unsigned* __restrict__ blksum,
                     unsigned* __restrict__ rowptr, unsigned* __restrict__ cursor)
{
    int i = blockIdx.x * 256 + threadIdx.x;
    if (i < kRN) {
        unsigned v = part[i] + blksum[i >> 10];
        rowptr[i] = v;
        cursor[i] = v;
    }
    if (i == 0) rowptr[kRN] = (unsigned)kRE;
}

// ---------------- CSR fill: colidx sorted by (relation,dst) ----------------
__global__ __launch_bounds__(256)
void fill_kernel(const int* __restrict__ src, const int* __restrict__ dst,
                 unsigned* __restrict__ cursor, int* __restrict__ colidx)
{
    int i = blockIdx.x * 256 + threadIdx.x;
    if (i < kRE) {
        int r = i / kE;
        int d = dst[i];
        unsigned pos = atomicAdd(&cursor[r * kN + d], 1u);
        colidx[pos] = src[i];
    }
}

// ---------------- W_r = sum_b coeff[r,b] * basis[b]  ([R,D,D] == [384,128]) ----------------
__global__ __launch_bounds__(256)
void wbuild_kernel(const float* __restrict__ basis, const float* __restrict__ coeff,
                   float* __restrict__ W)
{
    int i = blockIdx.x * 256 + threadIdx.x;
    if (i < kR * kD * kD) {
        int r = i / (kD * kD);
        int m = i - r * kD * kD;
        W[i] = coeff[r * kB] * basis[m] + coeff[r * kB + 1] * basis[kD * kD + m];
    }
}

// ---------------- gather: a[n, r*128+c] = invdeg[r,n] * sum_{e: dst=n,rel=r} in[src_e, c] ----------------
// one wave per (r, n) segment; 2 floats per lane.
template<bool RELUIN>
__global__ __launch_bounds__(256)
void gather_kernel(const float* __restrict__ in, const unsigned* __restrict__ rowptr,
                   const int* __restrict__ colidx, const float* __restrict__ invd,
                   float* __restrict__ a)
{
    const int lane = threadIdx.x & 63;
    const int seg = blockIdx.x * 4 + (threadIdx.x >> 6);   // 0 .. kRN-1 (grid exact)
    const int r = seg / kN;
    const int n = seg - r * kN;
    const unsigned beg = rowptr[seg], end = rowptr[seg + 1];
    float accx = 0.f, accy = 0.f;
    for (unsigned j = beg; j < end; ++j) {
        const int s = colidx[j];
        float2 v = *(const float2*)(in + (size_t)s * kD + lane * 2);
        if (RELUIN) { v.x = fmaxf(v.x, 0.f); v.y = fmaxf(v.y, 0.f); }
        accx += v.x; accy += v.y;
    }
    const float w = invd[seg];
    *(float2*)(a + (size_t)n * (kR * kD) + r * kD + lane * 2) = make_float2(accx * w, accy * w);
}

// ---------------- C[M,128] = op(A)[M,KD] @ W[KD,128] (+bias) (+Cin) (relu?) ----------------
// 256 threads, BM=128, BN=128, BK=16; 8x8 accumulators per thread.
template<int KD, bool RELUA, bool HASBIAS, bool ACCUM, bool RELUOUT>
__global__ __launch_bounds__(256)
void gemm_kernel(const float* __restrict__ A, const float* __restrict__ W,
                 const float* __restrict__ bias, const float* __restrict__ Cin,
                 float* __restrict__ Cout, int M)
{
    __shared__ float As[16 * 128];   // As[k][m] (transposed)
    __shared__ float Bs[16 * 128];   // Bs[k][o]
    const int tid = threadIdx.x;
    const int bm = blockIdx.x * 128;

    const int ty = tid >> 4;          // 0..15
    const int tx = tid & 15;          // 0..15
    const int lrow = tid >> 1;        // 0..127: A staging row
    const int lk = (tid & 1) * 8;     // 0 or 8: A staging k-offset
    const int grow = bm + lrow;

    float acc[8][8];
    #pragma unroll
    for (int i = 0; i < 8; ++i)
        #pragma unroll
        for (int j = 0; j < 8; ++j) acc[i][j] = 0.0f;

    for (int kt = 0; kt < KD / 16; ++kt) {
        float4 a0 = make_float4(0.f, 0.f, 0.f, 0.f);
        float4 a1 = make_float4(0.f, 0.f, 0.f, 0.f);
        if (grow < M) {
            const float* ap = A + (size_t)grow * KD + kt * 16 + lk;
            a0 = *(const float4*)ap;
            a1 = *(const float4*)(ap + 4);
        }
        if (RELUA) {
            a0.x = fmaxf(a0.x, 0.f); a0.y = fmaxf(a0.y, 0.f);
            a0.z = fmaxf(a0.z, 0.f); a0.w = fmaxf(a0.w, 0.f);
            a1.x = fmaxf(a1.x, 0.f); a1.y = fmaxf(a1.y, 0.f);
            a1.z = fmaxf(a1.z, 0.f); a1.w = fmaxf(a1.w, 0.f);
        }
        const float* wp = W + (size_t)(kt * 16 + ty) * kD + tx * 8;
        const float4 b0 = *(const float4*)wp;
        const float4 b1 = *(const float4*)(wp + 4);

        __syncthreads();
        As[(lk + 0) * 128 + lrow] = a0.x;
        As[(lk + 1) * 128 + lrow] = a0.y;
        As[(lk + 2) * 128 + lrow] = a0.z;
        As[(lk + 3) * 128 + lrow] = a0.w;
        As[(lk + 4) * 128 + lrow] = a1.x;
        As[(lk + 5) * 128 + lrow] = a1.y;
        As[(lk + 6) * 128 + lrow] = a1.z;
        As[(lk + 7) * 128 + lrow] = a1.w;
        *(float4*)&Bs[ty * 128 + tx * 8]     = b0;
        *(float4*)&Bs[ty * 128 + tx * 8 + 4] = b1;
        __syncthreads();

        #pragma unroll
        for (int kk = 0; kk < 16; ++kk) {
            const float4 av0 = *(const float4*)&As[kk * 128 + ty * 8];
            const float4 av1 = *(const float4*)&As[kk * 128 + ty * 8 + 4];
            const float4 bv0 = *(const float4*)&Bs[kk * 128 + tx * 8];
            const float4 bv1 = *(const float4*)&Bs[kk * 128 + tx * 8 + 4];
            const float a[8] = {av0.x, av0.y, av0.z, av0.w, av1.x, av1.y, av1.z, av1.w};
            const float b[8] = {bv0.x, bv0.y, bv0.z, bv0.w, bv1.x, bv1.y, bv1.z, bv1.w};
            #pragma unroll
            for (int i = 0; i < 8; ++i)
                #pragma unroll
                for (int j = 0; j < 8; ++j)
                    acc[i][j] = fmaf(a[i], b[j], acc[i][j]);
        }
    }

    float bb[8];
    #pragma unroll
    for (int j = 0; j < 8; ++j) bb[j] = HASBIAS ? bias[tx * 8 + j] : 0.0f;

    #pragma unroll
    for (int i = 0; i < 8; ++i) {
        const int row = bm + ty * 8 + i;
        if (row < M) {
            float o[8];
            #pragma unroll
            for (int j = 0; j < 8; ++j) o[j] = acc[i][j] + bb[j];
            if (ACCUM) {
                const float* cp = Cin + (size_t)row * kD + tx * 8;
                const float4 c0 = *(const float4*)cp;
                const float4 c1 = *(const float4*)(cp + 4);
                o[0] += c0.x; o[1] += c0.y; o[2] += c0.z; o[3] += c0.w;
                o[4] += c1.x; o[5] += c1.y; o[6] += c1.z; o[7] += c1.w;
            }
            if (RELUOUT) {
                #pragma unroll
                for (int j = 0; j < 8; ++j) o[j] = fmaxf(o[j], 0.f);
            }
            float* cp = Cout + (size_t)row * kD + tx * 8;
            *(float4*)cp       = make_float4(o[0], o[1], o[2], o[3]);
            *(float4*)(cp + 4) = make_float4(o[4], o[5], o[6], o[7]);
        }
    }
}

extern "C" void kernel_launch(void* const* d_in, const int* in_sizes, int n_in,
                              void* d_out, int out_size, void* d_ws, size_t ws_size,
                              hipStream_t stream)
{
    const float* x      = (const float*)d_in[0];
    const int*   esrc   = (const int*)d_in[1];
    const int*   edst   = (const int*)d_in[2];
    const float* proj_w = (const float*)d_in[3];
    const float* proj_b = (const float*)d_in[4];
    const float* basis1 = (const float*)d_in[5];
    const float* coeff1 = (const float*)d_in[6];
    const float* bias1  = (const float*)d_in[7];
    const float* loop1  = (const float*)d_in[8];
    const float* basis2 = (const float*)d_in[9];
    const float* coeff2 = (const float*)d_in[10];
    const float* bias2  = (const float*)d_in[11];
    const float* loop2  = (const float*)d_in[12];

    // ---- workspace layout ----
    float* ws = (float*)d_ws;
    float* h     = ws;                               // N*128
    float* a     = h + (size_t)kN * kD;              // N*384
    float* Wstk1 = a + (size_t)kN * kR * kD;         // 384*128
    float* Wstk2 = Wstk1 + (size_t)kR * kD * kD;     // 384*128
    float* invd  = Wstk2 + (size_t)kR * kD * kD;     // R*N
    unsigned* cnt    = (unsigned*)(invd + kRN);      // R*N
    unsigned* part   = cnt + kRN;                    // R*N
    unsigned* rowptr = part + kRN;                   // R*N+1
    unsigned* cursor = rowptr + kRN + 1;             // R*N
    unsigned* blksum = cursor + kRN;                 // kNB
    int* colidx      = (int*)(blksum + kNB + 1);     // R*E

    // ---- CSR build (edges shared by both layers) ----
    hipMemsetAsync(cnt, 0, sizeof(unsigned) * (size_t)kRN, stream);
    count_deg_kernel<<<(kRE + 255) / 256, 256, 0, stream>>>(edst, cnt);
    invdeg_kernel<<<(kRN + 255) / 256, 256, 0, stream>>>(cnt, invd);
    scan_block_kernel<<<kNB, 256, 0, stream>>>(cnt, part, blksum);
    scan_tops_kernel<<<1, 64, 0, stream>>>(blksum);
    scan_add_kernel<<<(kRN + 255) / 256, 256, 0, stream>>>(part, blksum, rowptr, cursor);
    fill_kernel<<<(kRE + 255) / 256, 256, 0, stream>>>(esrc, edst, cursor, colidx);

    wbuild_kernel<<<(kR * kD * kD + 255) / 256, 256, 0, stream>>>(basis1, coeff1, Wstk1);
    wbuild_kernel<<<(kR * kD * kD + 255) / 256, 256, 0, stream>>>(basis2, coeff2, Wstk2);

    const int gblocks = (kN + 127) / 128;
    const int gatherblocks = kRN / 4;   // 75000, exact
    float* g1 = (float*)d_out;

    // ---- projection: h = x @ proj_w + proj_b ----
    gemm_kernel<128, false, true, false, false><<<gblocks, 256, 0, stream>>>(
        x, proj_w, proj_b, nullptr, h, kN);

    // ---- layer 1 ----
    gemm_kernel<128, false, true, false, false><<<gblocks, 256, 0, stream>>>(
        h, loop1, bias1, nullptr, g1, kN);                       // g1 = h@loop1 + bias1
    gather_kernel<false><<<gatherblocks, 256, 0, stream>>>(h, rowptr, colidx, invd, a);
    gemm_kernel<384, false, false, true, false><<<gblocks, 256, 0, stream>>>(
        a, Wstk1, nullptr, g1, g1, kN);                          // g1 += a @ Wstk1 (pre-act)

    // ---- layer 2 (input = relu(g1), applied on read) ----
    gemm_kernel<128, true, true, false, false><<<gblocks, 256, 0, stream>>>(
        g1, loop2, bias2, nullptr, h, kN);                       // h = relu(g1)@loop2 + bias2
    gather_kernel<true><<<gatherblocks, 256, 0, stream>>>(g1, rowptr, colidx, invd, a);
    gemm_kernel<384, false, false, true, true><<<gblocks, 256, 0, stream>>>(
        a, Wstk2, nullptr, h, (float*)d_out, kN);                // out = relu(h + a @ Wstk2)
}

// Round 3
// 871.344 us; speedup vs baseline: 3.6043x; 1.3045x over previous
//
#include <hip/hip_runtime.h>

typedef unsigned int uint;
typedef unsigned short ushort;
typedef __attribute__((ext_vector_type(8))) short bf16x8;   // 8 bf16 in 4 VGPRs
typedef __attribute__((ext_vector_type(4))) float f32x4;

namespace {
constexpr int kN = 100000;   // nodes
constexpr int kD = 128;      // feature dim
constexpr int kR = 3;        // relations
constexpr int kE = 500000;   // edges per relation
constexpr int kB = 2;        // bases
constexpr int kRN = kR * kN;          // 300000 segments
constexpr int kRE = kR * kE;          // 1500000 edges
constexpr int kNB = (kRN + 1023) / 1024;  // scan blocks (293)
constexpr int kKS = kR * kD;          // stacked K = 384
}

__device__ __forceinline__ ushort f2bf(float f) {
    uint u = __builtin_bit_cast(uint, f);
    u += 0x7fff + ((u >> 16) & 1);           // RNE
    return (ushort)(u >> 16);
}
__device__ __forceinline__ float bf2f(ushort h) {
    return __builtin_bit_cast(float, (uint)h << 16);
}

// ---------------- degree counting ----------------
__global__ __launch_bounds__(256)
void count_deg_kernel(const int* __restrict__ dst, unsigned* __restrict__ cnt)
{
    int i = blockIdx.x * 256 + threadIdx.x;
    if (i < kRE) {
        int r = i / kE;
        atomicAdd(&cnt[r * kN + dst[i]], 1u);
    }
}

__global__ __launch_bounds__(256)
void invdeg_kernel(const unsigned* __restrict__ cnt, float* __restrict__ inv)
{
    int i = blockIdx.x * 256 + threadIdx.x;
    if (i < kRN) {
        unsigned c = cnt[i];
        inv[i] = 1.0f / (float)(c > 1u ? c : 1u);
    }
}

// ---------------- exclusive scan of cnt -> rowptr ----------------
__global__ __launch_bounds__(256)
void scan_block_kernel(const unsigned* __restrict__ cnt, unsigned* __restrict__ part,
                       unsigned* __restrict__ blksum)
{
    __shared__ unsigned s[256];
    const int tid = threadIdx.x;
    const int base = blockIdx.x * 1024 + tid * 4;
    unsigned v[4], sum = 0;
    #pragma unroll
    for (int j = 0; j < 4; ++j) {
        v[j] = (base + j < kRN) ? cnt[base + j] : 0u;
        sum += v[j];
    }
    s[tid] = sum;
    __syncthreads();
    #pragma unroll
    for (int off = 1; off < 256; off <<= 1) {
        unsigned t = (tid >= off) ? s[tid - off] : 0u;
        __syncthreads();
        s[tid] += t;
        __syncthreads();
    }
    unsigned run = s[tid] - sum;
    if (tid == 255) blksum[blockIdx.x] = s[255];
    #pragma unroll
    for (int j = 0; j < 4; ++j) {
        if (base + j < kRN) part[base + j] = run;
        run += v[j];
    }
}

__global__ void scan_tops_kernel(unsigned* __restrict__ blksum)
{
    if (threadIdx.x == 0 && blockIdx.x == 0) {
        unsigned run = 0;
        for (int i = 0; i < kNB; ++i) {
            unsigned t = blksum[i];
            blksum[i] = run;
            run += t;
        }
    }
}

__global__ __launch_bounds__(256)
void scan_add_kernel(const unsigned* __restrict__ part, const unsigned* __restrict__ blksum,
                     unsigned* __restrict__ rowptr, unsigned* __restrict__ cursor)
{
    int i = blockIdx.x * 256 + threadIdx.x;
    if (i < kRN) {
        unsigned v = part[i] + blksum[i >> 10];
        rowptr[i] = v;
        cursor[i] = v;
    }
    if (i == 0) rowptr[kRN] = (unsigned)kRE;
}

// ---------------- CSR fill ----------------
__global__ __launch_bounds__(256)
void fill_kernel(const int* __restrict__ src, const int* __restrict__ dst,
                 unsigned* __restrict__ cursor, int* __restrict__ colidx)
{
    int i = blockIdx.x * 256 + threadIdx.x;
    if (i < kRE) {
        int r = i / kE;
        int d = dst[i];
        unsigned pos = atomicAdd(&cursor[r * kN + d], 1u);
        colidx[pos] = src[i];
    }
}

// ---------------- WT build: stacked  WT[out][r*128+d] = sum_b coeff[r,b]*basis[b][d][out] ----------------
__global__ __launch_bounds__(256)
void wbuildT_kernel(const float* __restrict__ basis, const float* __restrict__ coeff,
                    ushort* __restrict__ WT)
{
    int i = blockIdx.x * 256 + threadIdx.x;   // over 128*384
    if (i < kD * kKS) {
        int out = i / kKS;
        int j = i - out * kKS;
        int r = j >> 7, d = j & 127;
        float v = coeff[r * kB] * basis[(size_t)d * kD + out]
                + coeff[r * kB + 1] * basis[(size_t)kD * kD + d * kD + out];
        WT[i] = f2bf(v);
    }
}

// ---------------- WT build: square  WT[out][k] = W[k][out] ----------------
__global__ __launch_bounds__(256)
void transposeW_kernel(const float* __restrict__ W, ushort* __restrict__ WT)
{
    int i = blockIdx.x * 256 + threadIdx.x;   // over 128*128
    if (i < kD * kD) {
        int out = i >> 7, k = i & 127;
        WT[i] = f2bf(W[k * kD + out]);
    }
}

// ---------------- gather (bf16): a[n, r*128+c] = invdeg[r,n] * sum in[src, c] ----------------
__global__ __launch_bounds__(256)
void gather_kernel(const ushort* __restrict__ in, const unsigned* __restrict__ rowptr,
                   const int* __restrict__ colidx, const float* __restrict__ invd,
                   ushort* __restrict__ a)
{
    const int lane = threadIdx.x & 63;
    const int seg = blockIdx.x * 4 + (threadIdx.x >> 6);   // grid exact
    const int r = seg / kN;
    const int n = seg - r * kN;
    const unsigned beg = rowptr[seg], end = rowptr[seg + 1];
    float ax = 0.f, ay = 0.f;
    for (unsigned j = beg; j < end; ++j) {
        const int s = colidx[j];
        uint v = *(const uint*)(in + (size_t)s * kD + lane * 2);
        ax += bf2f((ushort)(v & 0xffffu));
        ay += bf2f((ushort)(v >> 16));
    }
    const float w = invd[seg];
    uint o = (uint)f2bf(ax * w) | ((uint)f2bf(ay * w) << 16);
    *(uint*)(a + (size_t)n * kKS + r * kD + lane * 2) = o;
}

// ---------------- MFMA GEMM: C[M,128] = A[M,KD](bf16|fp32->bf16) @ W[KD,128] ----------------
// W passed as WT[128][KD] (pre-transposed, bf16). 256 thr, 4 waves 2x2 of 64x64.
// LDS tiles [128][64] bf16, XOR-swizzled (16B chunk index ^= row&7). Linear ds_write.
template<int KD, bool AFP32, bool HASBIAS, bool ACCUM, bool RELUOUT, bool OUTBF16>
__global__ __launch_bounds__(256)
void mfma_gemm(const void* __restrict__ Araw, const ushort* __restrict__ WT,
               const float* __restrict__ bias, const float* __restrict__ Cin,
               void* __restrict__ Cout, int M)
{
    constexpr int NT = KD / 64;
    __shared__ ushort As[128 * 64];
    __shared__ ushort Bs[128 * 64];
    const int tid  = threadIdx.x;
    const int bm   = blockIdx.x * 128;
    const int lane = tid & 63;
    const int w    = tid >> 6;
    const int wrow = (w >> 1) * 64;
    const int wcol = (w & 1) * 64;

    f32x4 acc[4][4];
    #pragma unroll
    for (int i = 0; i < 4; ++i)
        #pragma unroll
        for (int j = 0; j < 4; ++j)
            acc[i][j] = (f32x4){0.f, 0.f, 0.f, 0.f};

    // staging: 4 chunks each of A and B per thread per tile; chunk m -> (row=m>>3, oL=m&7),
    // source octet o = oL ^ (row&7)  (XOR swizzle applied via source address; dest linear).
    uint4 a4[4], b4[4];
    int arowL[4], osrcL[4];
    #pragma unroll
    for (int st = 0; st < 4; ++st) {
        const int m = st * 256 + tid;
        const int row = m >> 3;
        arowL[st] = row;
        osrcL[st] = (m & 7) ^ (row & 7);
    }

    auto load_tile = [&](int kt) {
        #pragma unroll
        for (int st = 0; st < 4; ++st) {
            const int row = arowL[st];
            const int osrc = osrcL[st];
            int arow = bm + row; if (arow >= M) arow = M - 1;   // clamp: safe, rows>=M unused
            if (AFP32) {
                const float* ap = (const float*)Araw + (size_t)arow * KD + kt * 64 + osrc * 8;
                const float4 f0 = *(const float4*)ap;
                const float4 f1 = *(const float4*)(ap + 4);
                a4[st].x = (uint)f2bf(f0.x) | ((uint)f2bf(f0.y) << 16);
                a4[st].y = (uint)f2bf(f0.z) | ((uint)f2bf(f0.w) << 16);
                a4[st].z = (uint)f2bf(f1.x) | ((uint)f2bf(f1.y) << 16);
                a4[st].w = (uint)f2bf(f1.z) | ((uint)f2bf(f1.w) << 16);
            } else {
                a4[st] = *(const uint4*)((const ushort*)Araw + (size_t)arow * KD + kt * 64 + osrc * 8);
            }
            b4[st] = *(const uint4*)(WT + (size_t)row * KD + kt * 64 + osrc * 8);
        }
    };

    load_tile(0);
    for (int kt = 0; kt < NT; ++kt) {
        __syncthreads();   // previous compute done reading LDS
        #pragma unroll
        for (int st = 0; st < 4; ++st) {
            const int m = st * 256 + tid;
            *(uint4*)&As[m * 8] = a4[st];
            *(uint4*)&Bs[m * 8] = b4[st];
        }
        __syncthreads();
        if (kt + 1 < NT) load_tile(kt + 1);   // prefetch next tile under MFMA

        #pragma unroll
        for (int ks = 0; ks < 2; ++ks) {
            const int oq = ks * 4 + (lane >> 4);
            bf16x8 af[4], bfr[4];
            #pragma unroll
            for (int am = 0; am < 4; ++am) {
                const int row = wrow + am * 16 + (lane & 15);
                const int oL = oq ^ (row & 7);
                af[am] = *(const bf16x8*)&As[row * 64 + oL * 8];
            }
            #pragma unroll
            for (int bn = 0; bn < 4; ++bn) {
                const int row = wcol + bn * 16 + (lane & 15);
                const int oL = oq ^ (row & 7);
                bfr[bn] = *(const bf16x8*)&Bs[row * 64 + oL * 8];
            }
            #pragma unroll
            for (int am = 0; am < 4; ++am)
                #pragma unroll
                for (int bn = 0; bn < 4; ++bn)
                    acc[am][bn] = __builtin_amdgcn_mfma_f32_16x16x32_bf16(
                        af[am], bfr[bn], acc[am][bn], 0, 0, 0);
        }
    }

    // epilogue: D row = bm+wrow+am*16+4*(lane>>4)+r ; col = wcol+bn*16+(lane&15)
    const int ccol = wcol + (lane & 15);
    float bb[4];
    #pragma unroll
    for (int bn = 0; bn < 4; ++bn) bb[bn] = HASBIAS ? bias[ccol + bn * 16] : 0.f;

    const int crow0 = bm + wrow + 4 * (lane >> 4);
    #pragma unroll
    for (int am = 0; am < 4; ++am) {
        #pragma unroll
        for (int r = 0; r < 4; ++r) {
            const int row = crow0 + am * 16 + r;
            if (row < M) {
                #pragma unroll
                for (int bn = 0; bn < 4; ++bn) {
                    float v = acc[am][bn][r] + bb[bn];
                    if (ACCUM) v += Cin[(size_t)row * kD + ccol + bn * 16];
                    if (RELUOUT) v = fmaxf(v, 0.f);
                    if (OUTBF16)
                        ((ushort*)Cout)[(size_t)row * kD + ccol + bn * 16] = f2bf(v);
                    else
                        ((float*)Cout)[(size_t)row * kD + ccol + bn * 16] = v;
                }
            }
        }
    }
}

extern "C" void kernel_launch(void* const* d_in, const int* in_sizes, int n_in,
                              void* d_out, int out_size, void* d_ws, size_t ws_size,
                              hipStream_t stream)
{
    const float* x      = (const float*)d_in[0];
    const int*   esrc   = (const int*)d_in[1];
    const int*   edst   = (const int*)d_in[2];
    const float* proj_w = (const float*)d_in[3];
    const float* proj_b = (const float*)d_in[4];
    const float* basis1 = (const float*)d_in[5];
    const float* coeff1 = (const float*)d_in[6];
    const float* bias1  = (const float*)d_in[7];
    const float* loop1  = (const float*)d_in[8];
    const float* basis2 = (const float*)d_in[9];
    const float* coeff2 = (const float*)d_in[10];
    const float* bias2  = (const float*)d_in[11];
    const float* loop2  = (const float*)d_in[12];

    // ---- workspace layout (bytes) ----
    char* p = (char*)d_ws;
    ushort* hb    = (ushort*)p;  p += (size_t)kN * kD * 2;        // 25.6 MB (bf16 h)
    ushort* ab    = (ushort*)p;  p += (size_t)kN * kKS * 2;       // 76.8 MB (bf16 gathered)
    ushort* r1b   = (ushort*)p;  p += (size_t)kN * kD * 2;        // 25.6 MB (bf16 relu(g1))
    ushort* WTp   = (ushort*)p;  p += (size_t)kD * kD * 2;        // proj_w^T
    ushort* WTl1  = (ushort*)p;  p += (size_t)kD * kD * 2;        // loop1^T
    ushort* WTl2  = (ushort*)p;  p += (size_t)kD * kD * 2;        // loop2^T
    ushort* WTs1  = (ushort*)p;  p += (size_t)kD * kKS * 2;       // stacked W1^T
    ushort* WTs2  = (ushort*)p;  p += (size_t)kD * kKS * 2;       // stacked W2^T
    float* invd   = (float*)p;   p += (size_t)kRN * 4;
    unsigned* cnt    = (unsigned*)p;  p += (size_t)kRN * 4;
    unsigned* part   = (unsigned*)p;  p += (size_t)kRN * 4;
    unsigned* rowptr = (unsigned*)p;  p += (size_t)(kRN + 1) * 4;
    unsigned* cursor = (unsigned*)p;  p += (size_t)kRN * 4;
    unsigned* blksum = (unsigned*)p;  p += (size_t)(kNB + 1) * 4;
    int* colidx      = (int*)p;       p += (size_t)kRE * 4;

    float* g1 = (float*)d_out;    // fp32 accumulator (reused: g1, then h2, then final out)

    // ---- CSR build (edges shared by both layers) ----
    hipMemsetAsync(cnt, 0, sizeof(unsigned) * (size_t)kRN, stream);
    count_deg_kernel<<<(kRE + 255) / 256, 256, 0, stream>>>(edst, cnt);
    invdeg_kernel<<<(kRN + 255) / 256, 256, 0, stream>>>(cnt, invd);
    scan_block_kernel<<<kNB, 256, 0, stream>>>(cnt, part, blksum);
    scan_tops_kernel<<<1, 64, 0, stream>>>(blksum);
    scan_add_kernel<<<(kRN + 255) / 256, 256, 0, stream>>>(part, blksum, rowptr, cursor);
    fill_kernel<<<(kRE + 255) / 256, 256, 0, stream>>>(esrc, edst, cursor, colidx);

    // ---- weight prep (bf16, transposed) ----
    transposeW_kernel<<<(kD * kD + 255) / 256, 256, 0, stream>>>(proj_w, WTp);
    transposeW_kernel<<<(kD * kD + 255) / 256, 256, 0, stream>>>(loop1, WTl1);
    transposeW_kernel<<<(kD * kD + 255) / 256, 256, 0, stream>>>(loop2, WTl2);
    wbuildT_kernel<<<(kD * kKS + 255) / 256, 256, 0, stream>>>(basis1, coeff1, WTs1);
    wbuildT_kernel<<<(kD * kKS + 255) / 256, 256, 0, stream>>>(basis2, coeff2, WTs2);

    const int gblocks = (kN + 127) / 128;   // 782
    const int gatherblocks = kRN / 4;       // 75000 exact

    // ---- projection: hb = bf16(x @ proj_w + proj_b) ----
    mfma_gemm<128, true, true, false, false, true><<<gblocks, 256, 0, stream>>>(
        x, WTp, proj_b, nullptr, hb, kN);

    // ---- layer 1 ----
    mfma_gemm<128, false, true, false, false, false><<<gblocks, 256, 0, stream>>>(
        hb, WTl1, bias1, nullptr, g1, kN);                    // g1 = h@loop1 + bias1 (fp32)
    gather_kernel<<<gatherblocks, 256, 0, stream>>>(hb, rowptr, colidx, invd, ab);
    mfma_gemm<384, false, false, true, true, true><<<gblocks, 256, 0, stream>>>(
        ab, WTs1, nullptr, g1, r1b, kN);                      // r1b = bf16(relu(g1 + a@W1))

    // ---- layer 2 ----
    mfma_gemm<128, false, true, false, false, false><<<gblocks, 256, 0, stream>>>(
        r1b, WTl2, bias2, nullptr, g1, kN);                   // g1 = relu1@loop2 + bias2 (fp32)
    gather_kernel<<<gatherblocks, 256, 0, stream>>>(r1b, rowptr, colidx, invd, ab);
    mfma_gemm<384, false, false, true, true, false><<<gblocks, 256, 0, stream>>>(
        ab, WTs2, nullptr, g1, (float*)d_out, kN);            // out = relu(g1 + a@W2) (fp32)
}

// Round 4
// 711.649 us; speedup vs baseline: 4.4131x; 1.2244x over previous
//
#include <hip/hip_runtime.h>

typedef unsigned int uint;
typedef unsigned short ushort;
typedef __attribute__((ext_vector_type(8))) short bf16x8;   // 8 bf16 in 4 VGPRs
typedef __attribute__((ext_vector_type(4))) float f32x4;

namespace {
constexpr int kN = 100000;   // nodes
constexpr int kD = 128;      // feature dim
constexpr int kR = 3;        // relations
constexpr int kE = 500000;   // edges per relation
constexpr int kB = 2;        // bases
constexpr int kRN = kR * kN;          // 300000 segments
constexpr int kRE = kR * kE;          // 1500000 edges
constexpr int kNB = (kRN + 1023) / 1024;  // scan blocks (293)
constexpr int kKS = kR * kD;          // stacked K = 384
constexpr int kKC = kD + kKS;         // fused K = 512
}

__device__ __forceinline__ ushort f2bf(float f) {
    uint u = __builtin_bit_cast(uint, f);
    u += 0x7fff + ((u >> 16) & 1);           // RNE
    return (ushort)(u >> 16);
}
__device__ __forceinline__ float bf2f(ushort h) {
    return __builtin_bit_cast(float, (uint)h << 16);
}

// ---------------- degree counting ----------------
__global__ __launch_bounds__(256)
void count_deg_kernel(const int* __restrict__ dst, unsigned* __restrict__ cnt)
{
    int i = blockIdx.x * 256 + threadIdx.x;
    if (i < kRE) {
        int r = i / kE;
        atomicAdd(&cnt[r * kN + dst[i]], 1u);
    }
}

__global__ __launch_bounds__(256)
void invdeg_kernel(const unsigned* __restrict__ cnt, float* __restrict__ inv)
{
    int i = blockIdx.x * 256 + threadIdx.x;
    if (i < kRN) {
        unsigned c = cnt[i];
        inv[i] = 1.0f / (float)(c > 1u ? c : 1u);
    }
}

// ---------------- exclusive scan of cnt -> rowptr ----------------
__global__ __launch_bounds__(256)
void scan_block_kernel(const unsigned* __restrict__ cnt, unsigned* __restrict__ part,
                       unsigned* __restrict__ blksum)
{
    __shared__ unsigned s[256];
    const int tid = threadIdx.x;
    const int base = blockIdx.x * 1024 + tid * 4;
    unsigned v[4], sum = 0;
    #pragma unroll
    for (int j = 0; j < 4; ++j) {
        v[j] = (base + j < kRN) ? cnt[base + j] : 0u;
        sum += v[j];
    }
    s[tid] = sum;
    __syncthreads();
    #pragma unroll
    for (int off = 1; off < 256; off <<= 1) {
        unsigned t = (tid >= off) ? s[tid - off] : 0u;
        __syncthreads();
        s[tid] += t;
        __syncthreads();
    }
    unsigned run = s[tid] - sum;
    if (tid == 255) blksum[blockIdx.x] = s[255];
    #pragma unroll
    for (int j = 0; j < 4; ++j) {
        if (base + j < kRN) part[base + j] = run;
        run += v[j];
    }
}

__global__ void scan_tops_kernel(unsigned* __restrict__ blksum)
{
    if (threadIdx.x == 0 && blockIdx.x == 0) {
        unsigned run = 0;
        for (int i = 0; i < kNB; ++i) {
            unsigned t = blksum[i];
            blksum[i] = run;
            run += t;
        }
    }
}

__global__ __launch_bounds__(256)
void scan_add_kernel(const unsigned* __restrict__ part, const unsigned* __restrict__ blksum,
                     unsigned* __restrict__ rowptr, unsigned* __restrict__ cursor)
{
    int i = blockIdx.x * 256 + threadIdx.x;
    if (i < kRN) {
        unsigned v = part[i] + blksum[i >> 10];
        rowptr[i] = v;
        cursor[i] = v;
    }
    if (i == 0) rowptr[kRN] = (unsigned)kRE;
}

// ---------------- CSR fill ----------------
__global__ __launch_bounds__(256)
void fill_kernel(const int* __restrict__ src, const int* __restrict__ dst,
                 unsigned* __restrict__ cursor, int* __restrict__ colidx)
{
    int i = blockIdx.x * 256 + threadIdx.x;
    if (i < kRE) {
        int r = i / kE;
        int d = dst[i];
        unsigned pos = atomicAdd(&cursor[r * kN + d], 1u);
        colidx[pos] = src[i];
    }
}

// ---------------- combined weight build: WTc[out][k], k<128: loop^T; k>=128: stacked W^T ----------------
__global__ __launch_bounds__(256)
void wcomb_kernel(const float* __restrict__ loopW, const float* __restrict__ basis,
                  const float* __restrict__ coeff, ushort* __restrict__ WTc)
{
    int i = blockIdx.x * 256 + threadIdx.x;   // over 128*512
    if (i < kD * kKC) {
        int out = i >> 9;
        int k = i & (kKC - 1);
        float v;
        if (k < kD) {
            v = loopW[(size_t)k * kD + out];
        } else {
            int j = k - kD;
            int r = j >> 7, d = j & 127;
            v = coeff[r * kB] * basis[(size_t)d * kD + out]
              + coeff[r * kB + 1] * basis[(size_t)kD * kD + d * kD + out];
        }
        WTc[i] = f2bf(v);
    }
}

// ---------------- WT build: square  WT[out][k] = W[k][out] ----------------
__global__ __launch_bounds__(256)
void transposeW_kernel(const float* __restrict__ W, ushort* __restrict__ WT)
{
    int i = blockIdx.x * 256 + threadIdx.x;   // over 128*128
    if (i < kD * kD) {
        int out = i >> 7, k = i & 127;
        WT[i] = f2bf(W[k * kD + out]);
    }
}

// ---------------- x -> bf16 ----------------
__global__ __launch_bounds__(256)
void f2bf_kernel(const float* __restrict__ in, ushort* __restrict__ out)
{
    const int i = blockIdx.x * 256 + threadIdx.x;   // over N*D/4 exactly
    const float4 v = ((const float4*)in)[i];
    ushort4 o;
    o.x = f2bf(v.x); o.y = f2bf(v.y); o.z = f2bf(v.z); o.w = f2bf(v.w);
    ((ushort4*)out)[i] = o;
}

// ---------------- gather (bf16, 2 edges/wave + unroll2 = 4 rows in flight) ----------------
// a[n, r*128+c] = invdeg[r,n] * sum_{e in seg} in[src_e, c]
__global__ __launch_bounds__(256)
void gather_kernel(const ushort* __restrict__ in, const unsigned* __restrict__ rowptr,
                   const int* __restrict__ colidx, const float* __restrict__ invd,
                   ushort* __restrict__ a)
{
    const int tid  = threadIdx.x;
    const int lane = tid & 63;
    const int half = lane >> 5;          // edge slot within wave
    const int c    = lane & 31;          // 8-byte column chunk (4 bf16)
    const int seg  = blockIdx.x * 4 + (tid >> 6);   // grid exact
    const int r = seg / kN;
    const int n = seg - r * kN;
    const unsigned beg = rowptr[seg], end = rowptr[seg + 1];

    float s0 = 0.f, s1 = 0.f, s2 = 0.f, s3 = 0.f;
    unsigned j = beg + half;
    for (; j + 2 < end; j += 4) {        // 2 edges per half per iter
        const int e0 = colidx[j];
        const int e1 = colidx[j + 2];
        const uint2 v0 = *(const uint2*)(in + (size_t)e0 * kD + c * 4);
        const uint2 v1 = *(const uint2*)(in + (size_t)e1 * kD + c * 4);
        s0 += bf2f((ushort)(v0.x & 0xffffu)) + bf2f((ushort)(v1.x & 0xffffu));
        s1 += bf2f((ushort)(v0.x >> 16))     + bf2f((ushort)(v1.x >> 16));
        s2 += bf2f((ushort)(v0.y & 0xffffu)) + bf2f((ushort)(v1.y & 0xffffu));
        s3 += bf2f((ushort)(v0.y >> 16))     + bf2f((ushort)(v1.y >> 16));
    }
    if (j < end) {
        const int e0 = colidx[j];
        const uint2 v0 = *(const uint2*)(in + (size_t)e0 * kD + c * 4);
        s0 += bf2f((ushort)(v0.x & 0xffffu));
        s1 += bf2f((ushort)(v0.x >> 16));
        s2 += bf2f((ushort)(v0.y & 0xffffu));
        s3 += bf2f((ushort)(v0.y >> 16));
    }
    // combine the two half-wave partials
    s0 += __shfl_xor(s0, 32, 64);
    s1 += __shfl_xor(s1, 32, 64);
    s2 += __shfl_xor(s2, 32, 64);
    s3 += __shfl_xor(s3, 32, 64);
    if (half == 0) {
        const float w = invd[seg];
        uint2 o;
        o.x = (uint)f2bf(s0 * w) | ((uint)f2bf(s1 * w) << 16);
        o.y = (uint)f2bf(s2 * w) | ((uint)f2bf(s3 * w) << 16);
        *(uint2*)(a + (size_t)n * kKS + r * kD + c * 4) = o;
    }
}

// ---------------- MFMA GEMM: C[M,128] = [A0 | A1][M,NT*64] @ WT^T (+bias) ----------------
// A0: first NT0 64-chunks (row stride NT0*64), A1: remaining (row stride (NT-NT0)*64).
// WT: [128][NT*64] pre-transposed bf16. 256 thr, 4 waves 2x2 of 64x64.
// LDS tiles [128][64] bf16, XOR-swizzled (16B chunk index ^= row&7), linear ds_write.
template<int NT0, int NT, bool RELUOUT, bool OUTBF16>
__global__ __launch_bounds__(256)
void mfma_gemm(const ushort* __restrict__ A0, const ushort* __restrict__ A1,
               const ushort* __restrict__ WT, const float* __restrict__ bias,
               void* __restrict__ Cout, int M)
{
    __shared__ ushort As[128 * 64];
    __shared__ ushort Bs[128 * 64];
    const int tid  = threadIdx.x;
    const int bm   = blockIdx.x * 128;
    const int lane = tid & 63;
    const int w    = tid >> 6;
    const int wrow = (w >> 1) * 64;
    const int wcol = (w & 1) * 64;

    f32x4 acc[4][4];
    #pragma unroll
    for (int i = 0; i < 4; ++i)
        #pragma unroll
        for (int j = 0; j < 4; ++j)
            acc[i][j] = (f32x4){0.f, 0.f, 0.f, 0.f};

    uint4 a4[4], b4[4];
    int arowL[4], osrcL[4];
    #pragma unroll
    for (int st = 0; st < 4; ++st) {
        const int m = st * 256 + tid;
        const int row = m >> 3;
        arowL[st] = row;
        osrcL[st] = (m & 7) ^ (row & 7);
    }

    auto load_tile = [&](int kt) {
        #pragma unroll
        for (int st = 0; st < 4; ++st) {
            const int row = arowL[st];
            const int osrc = osrcL[st];
            int arow = bm + row; if (arow >= M) arow = M - 1;   // clamp: rows>=M unused
            const ushort* ap = (kt < NT0)
                ? A0 + (size_t)arow * (NT0 * 64) + kt * 64
                : A1 + (size_t)arow * ((NT - NT0) * 64) + (kt - NT0) * 64;
            a4[st] = *(const uint4*)(ap + osrc * 8);
            b4[st] = *(const uint4*)(WT + (size_t)row * (NT * 64) + kt * 64 + osrc * 8);
        }
    };

    load_tile(0);
    #pragma unroll
    for (int kt = 0; kt < NT; ++kt) {
        __syncthreads();
        #pragma unroll
        for (int st = 0; st < 4; ++st) {
            const int m = st * 256 + tid;
            *(uint4*)&As[m * 8] = a4[st];
            *(uint4*)&Bs[m * 8] = b4[st];
        }
        __syncthreads();
        if (kt + 1 < NT) load_tile(kt + 1);   // prefetch under MFMA

        #pragma unroll
        for (int ks = 0; ks < 2; ++ks) {
            const int oq = ks * 4 + (lane >> 4);
            bf16x8 af[4], bfr[4];
            #pragma unroll
            for (int am = 0; am < 4; ++am) {
                const int row = wrow + am * 16 + (lane & 15);
                const int oL = oq ^ (row & 7);
                af[am] = *(const bf16x8*)&As[row * 64 + oL * 8];
            }
            #pragma unroll
            for (int bn = 0; bn < 4; ++bn) {
                const int row = wcol + bn * 16 + (lane & 15);
                const int oL = oq ^ (row & 7);
                bfr[bn] = *(const bf16x8*)&Bs[row * 64 + oL * 8];
            }
            #pragma unroll
            for (int am = 0; am < 4; ++am)
                #pragma unroll
                for (int bn = 0; bn < 4; ++bn)
                    acc[am][bn] = __builtin_amdgcn_mfma_f32_16x16x32_bf16(
                        af[am], bfr[bn], acc[am][bn], 0, 0, 0);
        }
    }

    // epilogue: row = bm+wrow+am*16+4*(lane>>4)+r ; col = wcol+bn*16+(lane&15)
    const int ccol = wcol + (lane & 15);
    float bb[4];
    #pragma unroll
    for (int bn = 0; bn < 4; ++bn) bb[bn] = bias[ccol + bn * 16];

    const int crow0 = bm + wrow + 4 * (lane >> 4);
    #pragma unroll
    for (int am = 0; am < 4; ++am) {
        #pragma unroll
        for (int r = 0; r < 4; ++r) {
            const int row = crow0 + am * 16 + r;
            if (row < M) {
                #pragma unroll
                for (int bn = 0; bn < 4; ++bn) {
                    float v = acc[am][bn][r] + bb[bn];
                    if (RELUOUT) v = fmaxf(v, 0.f);
                    if (OUTBF16)
                        ((ushort*)Cout)[(size_t)row * kD + ccol + bn * 16] = f2bf(v);
                    else
                        ((float*)Cout)[(size_t)row * kD + ccol + bn * 16] = v;
                }
            }
        }
    }
}

extern "C" void kernel_launch(void* const* d_in, const int* in_sizes, int n_in,
                              void* d_out, int out_size, void* d_ws, size_t ws_size,
                              hipStream_t stream)
{
    const float* x      = (const float*)d_in[0];
    const int*   esrc   = (const int*)d_in[1];
    const int*   edst   = (const int*)d_in[2];
    const float* proj_w = (const float*)d_in[3];
    const float* proj_b = (const float*)d_in[4];
    const float* basis1 = (const float*)d_in[5];
    const float* coeff1 = (const float*)d_in[6];
    const float* bias1  = (const float*)d_in[7];
    const float* loop1  = (const float*)d_in[8];
    const float* basis2 = (const float*)d_in[9];
    const float* coeff2 = (const float*)d_in[10];
    const float* bias2  = (const float*)d_in[11];
    const float* loop2  = (const float*)d_in[12];

    // ---- workspace layout ----
    char* p = (char*)d_ws;
    ushort* xb    = (ushort*)p;  p += (size_t)kN * kD * 2;        // bf16 x
    ushort* hb    = (ushort*)p;  p += (size_t)kN * kD * 2;        // bf16 h (proj out)
    ushort* r1b   = (ushort*)p;  p += (size_t)kN * kD * 2;        // bf16 relu(layer1)
    ushort* ab    = (ushort*)p;  p += (size_t)kN * kKS * 2;       // bf16 gathered [N,384]
    ushort* WTp   = (ushort*)p;  p += (size_t)kD * kD * 2;        // proj_w^T
    ushort* WTc1  = (ushort*)p;  p += (size_t)kD * kKC * 2;       // [loop1 | Wstk1]^T
    ushort* WTc2  = (ushort*)p;  p += (size_t)kD * kKC * 2;       // [loop2 | Wstk2]^T
    float* invd   = (float*)p;   p += (size_t)kRN * 4;
    unsigned* cnt    = (unsigned*)p;  p += (size_t)kRN * 4;
    unsigned* part   = (unsigned*)p;  p += (size_t)kRN * 4;
    unsigned* rowptr = (unsigned*)p;  p += (size_t)(kRN + 1) * 4;
    unsigned* cursor = (unsigned*)p;  p += (size_t)kRN * 4;
    unsigned* blksum = (unsigned*)p;  p += (size_t)(kNB + 1) * 4;
    int* colidx      = (int*)p;       p += (size_t)kRE * 4;

    // ---- CSR build (edges shared by both layers) ----
    hipMemsetAsync(cnt, 0, sizeof(unsigned) * (size_t)kRN, stream);
    count_deg_kernel<<<(kRE + 255) / 256, 256, 0, stream>>>(edst, cnt);
    invdeg_kernel<<<(kRN + 255) / 256, 256, 0, stream>>>(cnt, invd);
    scan_block_kernel<<<kNB, 256, 0, stream>>>(cnt, part, blksum);
    scan_tops_kernel<<<1, 64, 0, stream>>>(blksum);
    scan_add_kernel<<<(kRN + 255) / 256, 256, 0, stream>>>(part, blksum, rowptr, cursor);
    fill_kernel<<<(kRE + 255) / 256, 256, 0, stream>>>(esrc, edst, cursor, colidx);

    // ---- weight & input prep ----
    transposeW_kernel<<<(kD * kD + 255) / 256, 256, 0, stream>>>(proj_w, WTp);
    wcomb_kernel<<<(kD * kKC + 255) / 256, 256, 0, stream>>>(loop1, basis1, coeff1, WTc1);
    wcomb_kernel<<<(kD * kKC + 255) / 256, 256, 0, stream>>>(loop2, basis2, coeff2, WTc2);
    f2bf_kernel<<<(kN * kD / 4) / 256, 256, 0, stream>>>(x, xb);

    const int gblocks = (kN + 127) / 128;   // 782
    const int gatherblocks = kRN / 4;       // 75000 exact

    // ---- projection: hb = bf16(x @ proj_w + proj_b) ----
    mfma_gemm<2, 2, false, true><<<gblocks, 256, 0, stream>>>(
        xb, nullptr, WTp, proj_b, hb, kN);

    // ---- layer 1: r1b = bf16(relu([h | gather(h)] @ [loop1|Wstk1] + bias1)) ----
    gather_kernel<<<gatherblocks, 256, 0, stream>>>(hb, rowptr, colidx, invd, ab);
    mfma_gemm<2, 8, true, true><<<gblocks, 256, 0, stream>>>(
        hb, ab, WTc1, bias1, r1b, kN);

    // ---- layer 2: out = relu([r1 | gather(r1)] @ [loop2|Wstk2] + bias2) (fp32) ----
    gather_kernel<<<gatherblocks, 256, 0, stream>>>(r1b, rowptr, colidx, invd, ab);
    mfma_gemm<2, 8, true, false><<<gblocks, 256, 0, stream>>>(
        r1b, ab, WTc2, bias2, d_out, kN);
}

// Round 5
// 641.778 us; speedup vs baseline: 4.8936x; 1.1089x over previous
//
#include <hip/hip_runtime.h>

typedef unsigned int uint;
typedef unsigned short ushort;
typedef __attribute__((ext_vector_type(8))) short bf16x8;   // 8 bf16 in 4 VGPRs
typedef __attribute__((ext_vector_type(4))) float f32x4;

namespace {
constexpr int kN = 100000;   // nodes
constexpr int kD = 128;      // feature dim
constexpr int kR = 3;        // relations
constexpr int kE = 500000;   // edges per relation
constexpr int kB = 2;        // bases
constexpr int kRN = kR * kN;              // 300000 segments
constexpr int kRE = kR * kE;              // 1500000 edges
constexpr int kNB = (kRN + 1023) / 1024;  // scan blocks (293)
constexpr int kKS = kR * kD;              // stacked K = 384
constexpr int kKC = kD + kKS;             // fused K = 512
constexpr int kNBK = (kN + 511) / 512;    // node buckets (196)
constexpr int kNQ = kR * kNBK;            // relation-buckets (588)
constexpr int kCB = (kRE + 2047) / 2048;  // edge-chunk blocks (733)
}

__device__ __forceinline__ ushort f2bf(float f) {
    uint u = __builtin_bit_cast(uint, f);
    u += 0x7fff + ((u >> 16) & 1);           // RNE
    return (ushort)(u >> 16);
}
__device__ __forceinline__ float bf2f(ushort h) {
    return __builtin_bit_cast(float, (uint)h << 16);
}
__device__ __forceinline__ int rel_of(int i) {
    return (i >= kE) + (i >= 2 * kE);
}

// ---------------- count: per-node degree + per-bucket edge count ----------------
__global__ __launch_bounds__(256)
void count_kernel(const int* __restrict__ dst, unsigned* __restrict__ cnt,
                  unsigned* __restrict__ bcnt)
{
    __shared__ unsigned bl[kNQ];
    const int tid = threadIdx.x;
    for (int q = tid; q < kNQ; q += 256) bl[q] = 0;
    __syncthreads();
    const int i0 = blockIdx.x * 2048 + tid * 8;
    if (i0 + 8 <= kRE) {
        const int4 d0 = *(const int4*)(dst + i0);
        const int4 d1 = *(const int4*)(dst + i0 + 4);
        const int dd[8] = {d0.x, d0.y, d0.z, d0.w, d1.x, d1.y, d1.z, d1.w};
        #pragma unroll
        for (int j = 0; j < 8; ++j) {
            const int r = rel_of(i0 + j);
            atomicAdd(&cnt[r * kN + dd[j]], 1u);
            atomicAdd(&bl[r * kNBK + (dd[j] >> 9)], 1u);
        }
    } else {
        for (int j = 0; j < 8; ++j) {
            const int i = i0 + j;
            if (i < kRE) {
                const int d = dst[i];
                const int r = rel_of(i);
                atomicAdd(&cnt[r * kN + d], 1u);
                atomicAdd(&bl[r * kNBK + (d >> 9)], 1u);
            }
        }
    }
    __syncthreads();
    for (int q = tid; q < kNQ; q += 256) {
        const unsigned c = bl[q];
        if (c) atomicAdd(&bcnt[q], c);
    }
}

// ---------------- exclusive scan of cnt -> rowptr ----------------
__global__ __launch_bounds__(256)
void scan_block_kernel(const unsigned* __restrict__ cnt, unsigned* __restrict__ part,
                       unsigned* __restrict__ blksum)
{
    __shared__ unsigned s[256];
    const int tid = threadIdx.x;
    const int base = blockIdx.x * 1024 + tid * 4;
    unsigned v[4], sum = 0;
    #pragma unroll
    for (int j = 0; j < 4; ++j) {
        v[j] = (base + j < kRN) ? cnt[base + j] : 0u;
        sum += v[j];
    }
    s[tid] = sum;
    __syncthreads();
    #pragma unroll
    for (int off = 1; off < 256; off <<= 1) {
        unsigned t = (tid >= off) ? s[tid - off] : 0u;
        __syncthreads();
        s[tid] += t;
        __syncthreads();
    }
    unsigned run = s[tid] - sum;
    if (tid == 255) blksum[blockIdx.x] = s[255];
    #pragma unroll
    for (int j = 0; j < 4; ++j) {
        if (base + j < kRN) part[base + j] = run;
        run += v[j];
    }
}

// serial top-level scans: blksum (293) and bcnt->boff/bcur (588)
__global__ void scan_tops_kernel(unsigned* __restrict__ blksum,
                                 const unsigned* __restrict__ bcnt,
                                 unsigned* __restrict__ boff, unsigned* __restrict__ bcur)
{
    if (threadIdx.x == 0) {
        unsigned run = 0;
        for (int i = 0; i < kNB; ++i) {
            unsigned t = blksum[i];
            blksum[i] = run;
            run += t;
        }
    } else if (threadIdx.x == 64) {
        unsigned run = 0;
        for (int q = 0; q < kNQ; ++q) {
            boff[q] = run;
            bcur[q] = run;
            run += bcnt[q];
        }
        boff[kNQ] = run;
    }
}

__global__ __launch_bounds__(256)
void scan_add_kernel(const unsigned* __restrict__ part, const unsigned* __restrict__ blksum,
                     const unsigned* __restrict__ cnt,
                     unsigned* __restrict__ rowptr, float* __restrict__ invd)
{
    int i = blockIdx.x * 256 + threadIdx.x;
    if (i < kRN) {
        rowptr[i] = part[i] + blksum[i >> 10];
        unsigned c = cnt[i];
        invd[i] = 1.0f / (float)(c > 1u ? c : 1u);
    }
    if (i == 0) rowptr[kRN] = (unsigned)kRE;
}

// ---------------- passB: bin edges into bucket-contiguous packed records ----------------
// record = (src << 9) | (dst & 511); bucket q = r*kNBK + (dst>>9)
__global__ __launch_bounds__(256)
void passB_kernel(const int* __restrict__ src, const int* __restrict__ dst,
                  unsigned* __restrict__ bcur, uint* __restrict__ colbkt)
{
    __shared__ unsigned bl[kNQ];     // local counts, then local cursors
    __shared__ unsigned base_l[kNQ];
    const int tid = threadIdx.x;
    for (int q = tid; q < kNQ; q += 256) bl[q] = 0;
    __syncthreads();
    const int i0 = blockIdx.x * 2048 + tid * 8;
    int dd[8], qq[8];
    const bool full = (i0 + 8 <= kRE);
    if (full) {
        const int4 d0 = *(const int4*)(dst + i0);
        const int4 d1 = *(const int4*)(dst + i0 + 4);
        dd[0]=d0.x; dd[1]=d0.y; dd[2]=d0.z; dd[3]=d0.w;
        dd[4]=d1.x; dd[5]=d1.y; dd[6]=d1.z; dd[7]=d1.w;
        #pragma unroll
        for (int j = 0; j < 8; ++j) {
            qq[j] = rel_of(i0 + j) * kNBK + (dd[j] >> 9);
            atomicAdd(&bl[qq[j]], 1u);
        }
    } else {
        for (int j = 0; j < 8; ++j) {
            const int i = i0 + j;
            qq[j] = -1;
            if (i < kRE) {
                dd[j] = dst[i];
                qq[j] = rel_of(i) * kNBK + (dd[j] >> 9);
                atomicAdd(&bl[qq[j]], 1u);
            }
        }
    }
    __syncthreads();
    for (int q = tid; q < kNQ; q += 256) {
        const unsigned c = bl[q];
        base_l[q] = c ? atomicAdd(&bcur[q], c) : 0u;
        bl[q] = 0;   // reuse as local cursor
    }
    __syncthreads();
    if (full) {
        const int4 s0 = *(const int4*)(src + i0);
        const int4 s1 = *(const int4*)(src + i0 + 4);
        const int ss[8] = {s0.x, s0.y, s0.z, s0.w, s1.x, s1.y, s1.z, s1.w};
        #pragma unroll
        for (int j = 0; j < 8; ++j) {
            const unsigned pos = base_l[qq[j]] + atomicAdd(&bl[qq[j]], 1u);
            colbkt[pos] = ((uint)ss[j] << 9) | (uint)(dd[j] & 511);
        }
    } else {
        for (int j = 0; j < 8; ++j) {
            if (qq[j] >= 0) {
                const unsigned pos = base_l[qq[j]] + atomicAdd(&bl[qq[j]], 1u);
                colbkt[pos] = ((uint)src[i0 + j] << 9) | (uint)(dd[j] & 511);
            }
        }
    }
}

// ---------------- passC: per-bucket scatter into final CSR colidx ----------------
__global__ __launch_bounds__(256)
void passC_kernel(const uint* __restrict__ colbkt, const unsigned* __restrict__ boff,
                  const unsigned* __restrict__ rowptr, int* __restrict__ colidx)
{
    __shared__ unsigned cur[512];
    const int tid = threadIdx.x;
    const int q = blockIdx.x;            // 0..kNQ-1
    const int r = q / kNBK;
    const int b = q - r * kNBK;
    const int n0 = b << 9;
    const int nn = min(512, kN - n0);
    for (int g = tid; g < nn; g += 256) cur[g] = rowptr[r * kN + n0 + g];
    __syncthreads();
    const unsigned e0 = boff[q], e1 = boff[q + 1];
    for (unsigned j = e0 + tid; j < e1; j += 256) {
        const uint p = colbkt[j];
        const unsigned pos = atomicAdd(&cur[p & 511u], 1u);
        colidx[pos] = (int)(p >> 9);
    }
}

// ---------------- fused weight prep ----------------
// blocks [0,64): WTp = proj_w^T (bf16); [64,320): WTc1; [320,576): WTc2
__device__ __forceinline__ void wcomb_one(int i, const float* loopW, const float* basis,
                                          const float* coeff, ushort* WTc)
{
    int out = i >> 9;
    int k = i & (kKC - 1);
    float v;
    if (k < kD) {
        v = loopW[(size_t)k * kD + out];
    } else {
        int j = k - kD;
        int r = j >> 7, d = j & 127;
        v = coeff[r * kB] * basis[(size_t)d * kD + out]
          + coeff[r * kB + 1] * basis[(size_t)kD * kD + d * kD + out];
    }
    WTc[i] = f2bf(v);
}

__global__ __launch_bounds__(256)
void prep_kernel(const float* __restrict__ proj_w,
                 const float* __restrict__ loop1, const float* __restrict__ basis1,
                 const float* __restrict__ coeff1,
                 const float* __restrict__ loop2, const float* __restrict__ basis2,
                 const float* __restrict__ coeff2,
                 ushort* __restrict__ WTp, ushort* __restrict__ WTc1,
                 ushort* __restrict__ WTc2)
{
    const int b = blockIdx.x;
    const int tid = threadIdx.x;
    if (b < 64) {
        const int i = b * 256 + tid;           // 16384
        const int out = i >> 7, k = i & 127;
        WTp[i] = f2bf(proj_w[(size_t)k * kD + out]);
    } else if (b < 320) {
        wcomb_one((b - 64) * 256 + tid, loop1, basis1, coeff1, WTc1);
    } else {
        wcomb_one((b - 320) * 256 + tid, loop2, basis2, coeff2, WTc2);
    }
}

// ---------------- gather: a[n, r*128+c] = invdeg[r,n] * sum in[src, c] ----------------
// 16-lane row groups (uint4 = 16B/lane), 4 groups/wave, unroll 2 -> 8 rows in flight.
__global__ __launch_bounds__(256)
void gather_kernel(const ushort* __restrict__ in, const unsigned* __restrict__ rowptr,
                   const int* __restrict__ colidx, const float* __restrict__ invd,
                   ushort* __restrict__ a)
{
    const int tid  = threadIdx.x;
    const int lane = tid & 63;
    const int grp  = lane >> 4;          // 0..3: edge slot
    const int c    = lane & 15;          // 16B column chunk
    const int seg  = blockIdx.x * 4 + (tid >> 6);   // grid exact
    const int r = seg / kN;
    const int n = seg - r * kN;
    const unsigned beg = rowptr[seg], end = rowptr[seg + 1];

    float s0=0.f,s1=0.f,s2=0.f,s3=0.f,s4=0.f,s5=0.f,s6=0.f,s7=0.f;
    unsigned j = beg + grp;
    for (; j + 4 < end; j += 8) {
        const int ea = colidx[j];
        const int eb = colidx[j + 4];
        const uint4 va = *(const uint4*)(in + (size_t)ea * kD + c * 8);
        const uint4 vb = *(const uint4*)(in + (size_t)eb * kD + c * 8);
        s0 += bf2f((ushort)(va.x & 0xffffu)) + bf2f((ushort)(vb.x & 0xffffu));
        s1 += bf2f((ushort)(va.x >> 16))     + bf2f((ushort)(vb.x >> 16));
        s2 += bf2f((ushort)(va.y & 0xffffu)) + bf2f((ushort)(vb.y & 0xffffu));
        s3 += bf2f((ushort)(va.y >> 16))     + bf2f((ushort)(vb.y >> 16));
        s4 += bf2f((ushort)(va.z & 0xffffu)) + bf2f((ushort)(vb.z & 0xffffu));
        s5 += bf2f((ushort)(va.z >> 16))     + bf2f((ushort)(vb.z >> 16));
        s6 += bf2f((ushort)(va.w & 0xffffu)) + bf2f((ushort)(vb.w & 0xffffu));
        s7 += bf2f((ushort)(va.w >> 16))     + bf2f((ushort)(vb.w >> 16));
    }
    if (j < end) {
        const int ea = colidx[j];
        const uint4 va = *(const uint4*)(in + (size_t)ea * kD + c * 8);
        s0 += bf2f((ushort)(va.x & 0xffffu));
        s1 += bf2f((ushort)(va.x >> 16));
        s2 += bf2f((ushort)(va.y & 0xffffu));
        s3 += bf2f((ushort)(va.y >> 16));
        s4 += bf2f((ushort)(va.z & 0xffffu));
        s5 += bf2f((ushort)(va.z >> 16));
        s6 += bf2f((ushort)(va.w & 0xffffu));
        s7 += bf2f((ushort)(va.w >> 16));
    }
    // reduce the 4 groups
    s0 += __shfl_xor(s0, 16, 64); s0 += __shfl_xor(s0, 32, 64);
    s1 += __shfl_xor(s1, 16, 64); s1 += __shfl_xor(s1, 32, 64);
    s2 += __shfl_xor(s2, 16, 64); s2 += __shfl_xor(s2, 32, 64);
    s3 += __shfl_xor(s3, 16, 64); s3 += __shfl_xor(s3, 32, 64);
    s4 += __shfl_xor(s4, 16, 64); s4 += __shfl_xor(s4, 32, 64);
    s5 += __shfl_xor(s5, 16, 64); s5 += __shfl_xor(s5, 32, 64);
    s6 += __shfl_xor(s6, 16, 64); s6 += __shfl_xor(s6, 32, 64);
    s7 += __shfl_xor(s7, 16, 64); s7 += __shfl_xor(s7, 32, 64);
    if (grp == 0) {
        const float w = invd[seg];
        uint4 o;
        o.x = (uint)f2bf(s0 * w) | ((uint)f2bf(s1 * w) << 16);
        o.y = (uint)f2bf(s2 * w) | ((uint)f2bf(s3 * w) << 16);
        o.z = (uint)f2bf(s4 * w) | ((uint)f2bf(s5 * w) << 16);
        o.w = (uint)f2bf(s6 * w) | ((uint)f2bf(s7 * w) << 16);
        *(uint4*)(a + (size_t)n * kKS + r * kD + c * 8) = o;
    }
}

// ---------------- MFMA GEMM: C[M,128] = [A0 | A1][M,NT*64] @ WT^T (+bias) ----------------
// A0: first NT0 64-chunks (fp32 if AFP32, else bf16; row stride NT0*64);
// A1: remaining chunks (bf16, row stride (NT-NT0)*64).
// WT: [128][NT*64] pre-transposed bf16. 256 thr, 4 waves 2x2 of 64x64.
// LDS tiles [128][64] bf16, XOR-swizzled (16B chunk index ^= row&7), linear ds_write.
template<int NT0, int NT, bool AFP32, bool RELUOUT, bool OUTBF16>
__global__ __launch_bounds__(256)
void mfma_gemm(const void* __restrict__ A0, const ushort* __restrict__ A1,
               const ushort* __restrict__ WT, const float* __restrict__ bias,
               void* __restrict__ Cout, int M)
{
    __shared__ ushort As[128 * 64];
    __shared__ ushort Bs[128 * 64];
    const int tid  = threadIdx.x;
    const int bm   = blockIdx.x * 128;
    const int lane = tid & 63;
    const int w    = tid >> 6;
    const int wrow = (w >> 1) * 64;
    const int wcol = (w & 1) * 64;

    f32x4 acc[4][4];
    #pragma unroll
    for (int i = 0; i < 4; ++i)
        #pragma unroll
        for (int j = 0; j < 4; ++j)
            acc[i][j] = (f32x4){0.f, 0.f, 0.f, 0.f};

    uint4 a4[4], b4[4];
    int arowL[4], osrcL[4];
    #pragma unroll
    for (int st = 0; st < 4; ++st) {
        const int m = st * 256 + tid;
        const int row = m >> 3;
        arowL[st] = row;
        osrcL[st] = (m & 7) ^ (row & 7);
    }

    auto load_tile = [&](int kt) {
        #pragma unroll
        for (int st = 0; st < 4; ++st) {
            const int row = arowL[st];
            const int osrc = osrcL[st];
            int arow = bm + row; if (arow >= M) arow = M - 1;   // clamp: rows>=M unused
            if (kt < NT0) {
                if (AFP32) {
                    const float* ap = (const float*)A0 + (size_t)arow * (NT0 * 64) + kt * 64 + osrc * 8;
                    const float4 f0 = *(const float4*)ap;
                    const float4 f1 = *(const float4*)(ap + 4);
                    a4[st].x = (uint)f2bf(f0.x) | ((uint)f2bf(f0.y) << 16);
                    a4[st].y = (uint)f2bf(f0.z) | ((uint)f2bf(f0.w) << 16);
                    a4[st].z = (uint)f2bf(f1.x) | ((uint)f2bf(f1.y) << 16);
                    a4[st].w = (uint)f2bf(f1.z) | ((uint)f2bf(f1.w) << 16);
                } else {
                    a4[st] = *(const uint4*)((const ushort*)A0 + (size_t)arow * (NT0 * 64) + kt * 64 + osrc * 8);
                }
            } else {
                a4[st] = *(const uint4*)(A1 + (size_t)arow * ((NT - NT0) * 64) + (kt - NT0) * 64 + osrc * 8);
            }
            b4[st] = *(const uint4*)(WT + (size_t)row * (NT * 64) + kt * 64 + osrc * 8);
        }
    };

    load_tile(0);
    #pragma unroll
    for (int kt = 0; kt < NT; ++kt) {
        __syncthreads();
        #pragma unroll
        for (int st = 0; st < 4; ++st) {
            const int m = st * 256 + tid;
            *(uint4*)&As[m * 8] = a4[st];
            *(uint4*)&Bs[m * 8] = b4[st];
        }
        __syncthreads();
        if (kt + 1 < NT) load_tile(kt + 1);   // prefetch under MFMA

        #pragma unroll
        for (int ks = 0; ks < 2; ++ks) {
            const int oq = ks * 4 + (lane >> 4);
            bf16x8 af[4], bfr[4];
            #pragma unroll
            for (int am = 0; am < 4; ++am) {
                const int row = wrow + am * 16 + (lane & 15);
                const int oL = oq ^ (row & 7);
                af[am] = *(const bf16x8*)&As[row * 64 + oL * 8];
            }
            #pragma unroll
            for (int bn = 0; bn < 4; ++bn) {
                const int row = wcol + bn * 16 + (lane & 15);
                const int oL = oq ^ (row & 7);
                bfr[bn] = *(const bf16x8*)&Bs[row * 64 + oL * 8];
            }
            #pragma unroll
            for (int am = 0; am < 4; ++am)
                #pragma unroll
                for (int bn = 0; bn < 4; ++bn)
                    acc[am][bn] = __builtin_amdgcn_mfma_f32_16x16x32_bf16(
                        af[am], bfr[bn], acc[am][bn], 0, 0, 0);
        }
    }

    // epilogue: row = bm+wrow+am*16+4*(lane>>4)+r ; col = wcol+bn*16+(lane&15)
    const int ccol = wcol + (lane & 15);
    float bb[4];
    #pragma unroll
    for (int bn = 0; bn < 4; ++bn) bb[bn] = bias[ccol + bn * 16];

    const int crow0 = bm + wrow + 4 * (lane >> 4);
    #pragma unroll
    for (int am = 0; am < 4; ++am) {
        #pragma unroll
        for (int r = 0; r < 4; ++r) {
            const int row = crow0 + am * 16 + r;
            if (row < M) {
                #pragma unroll
                for (int bn = 0; bn < 4; ++bn) {
                    float v = acc[am][bn][r] + bb[bn];
                    if (RELUOUT) v = fmaxf(v, 0.f);
                    if (OUTBF16)
                        ((ushort*)Cout)[(size_t)row * kD + ccol + bn * 16] = f2bf(v);
                    else
                        ((float*)Cout)[(size_t)row * kD + ccol + bn * 16] = v;
                }
            }
        }
    }
}

extern "C" void kernel_launch(void* const* d_in, const int* in_sizes, int n_in,
                              void* d_out, int out_size, void* d_ws, size_t ws_size,
                              hipStream_t stream)
{
    const float* x      = (const float*)d_in[0];
    const int*   esrc   = (const int*)d_in[1];
    const int*   edst   = (const int*)d_in[2];
    const float* proj_w = (const float*)d_in[3];
    const float* proj_b = (const float*)d_in[4];
    const float* basis1 = (const float*)d_in[5];
    const float* coeff1 = (const float*)d_in[6];
    const float* bias1  = (const float*)d_in[7];
    const float* loop1  = (const float*)d_in[8];
    const float* basis2 = (const float*)d_in[9];
    const float* coeff2 = (const float*)d_in[10];
    const float* bias2  = (const float*)d_in[11];
    const float* loop2  = (const float*)d_in[12];

    // ---- workspace layout ----
    char* p = (char*)d_ws;
    ushort* hb    = (ushort*)p;  p += (size_t)kN * kD * 2;        // bf16 h (proj out)
    ushort* r1b   = (ushort*)p;  p += (size_t)kN * kD * 2;        // bf16 relu(layer1)
    ushort* ab    = (ushort*)p;  p += (size_t)kN * kKS * 2;       // bf16 gathered [N,384]
    ushort* WTp   = (ushort*)p;  p += (size_t)kD * kD * 2;        // proj_w^T
    ushort* WTc1  = (ushort*)p;  p += (size_t)kD * kKC * 2;       // [loop1 | Wstk1]^T
    ushort* WTc2  = (ushort*)p;  p += (size_t)kD * kKC * 2;       // [loop2 | Wstk2]^T
    float* invd   = (float*)p;   p += (size_t)kRN * 4;
    unsigned* cnt    = (unsigned*)p;  p += (size_t)kRN * 4;       // cnt+bcnt adjacent: one memset
    unsigned* bcnt   = (unsigned*)p;  p += (size_t)kNQ * 4;
    unsigned* part   = (unsigned*)p;  p += (size_t)kRN * 4;
    unsigned* rowptr = (unsigned*)p;  p += (size_t)(kRN + 1) * 4;
    unsigned* blksum = (unsigned*)p;  p += (size_t)(kNB + 1) * 4;
    unsigned* boff   = (unsigned*)p;  p += (size_t)(kNQ + 1) * 4;
    unsigned* bcur   = (unsigned*)p;  p += (size_t)kNQ * 4;
    uint* colbkt     = (uint*)p;      p += (size_t)kRE * 4;
    int* colidx      = (int*)p;       p += (size_t)kRE * 4;

    // ---- CSR build (bucketed, write-amp-free; edges shared by both layers) ----
    hipMemsetAsync(cnt, 0, sizeof(unsigned) * (size_t)(kRN + kNQ), stream);
    count_kernel<<<kCB, 256, 0, stream>>>(edst, cnt, bcnt);
    scan_block_kernel<<<kNB, 256, 0, stream>>>(cnt, part, blksum);
    scan_tops_kernel<<<1, 128, 0, stream>>>(blksum, bcnt, boff, bcur);
    scan_add_kernel<<<(kRN + 255) / 256, 256, 0, stream>>>(part, blksum, cnt, rowptr, invd);
    passB_kernel<<<kCB, 256, 0, stream>>>(esrc, edst, bcur, colbkt);
    passC_kernel<<<kNQ, 256, 0, stream>>>(colbkt, boff, rowptr, colidx);

    // ---- fused weight prep ----
    prep_kernel<<<576, 256, 0, stream>>>(proj_w, loop1, basis1, coeff1,
                                         loop2, basis2, coeff2, WTp, WTc1, WTc2);

    const int gblocks = (kN + 127) / 128;   // 782
    const int gatherblocks = kRN / 4;       // 75000 exact

    // ---- projection: hb = bf16(x @ proj_w + proj_b), fp32 A read in-GEMM ----
    mfma_gemm<2, 2, true, false, true><<<gblocks, 256, 0, stream>>>(
        x, nullptr, WTp, proj_b, hb, kN);

    // ---- layer 1: r1b = bf16(relu([h | gather(h)] @ [loop1|Wstk1] + bias1)) ----
    gather_kernel<<<gatherblocks, 256, 0, stream>>>(hb, rowptr, colidx, invd, ab);
    mfma_gemm<2, 8, false, true, true><<<gblocks, 256, 0, stream>>>(
        hb, ab, WTc1, bias1, r1b, kN);

    // ---- layer 2: out = relu([r1 | gather(r1)] @ [loop2|Wstk2] + bias2) (fp32) ----
    gather_kernel<<<gatherblocks, 256, 0, stream>>>(r1b, rowptr, colidx, invd, ab);
    mfma_gemm<2, 8, false, true, false><<<gblocks, 256, 0, stream>>>(
        r1b, ab, WTc2, bias2, d_out, kN);
}

// Round 6
// 472.712 us; speedup vs baseline: 6.6438x; 1.3577x over previous
//
#include <hip/hip_runtime.h>

typedef unsigned int uint;
typedef unsigned short ushort;
typedef __attribute__((ext_vector_type(8))) short bf16x8;   // 8 bf16 in 4 VGPRs
typedef __attribute__((ext_vector_type(4))) float f32x4;

namespace {
constexpr int kN = 100000;   // nodes
constexpr int kD = 128;      // feature dim
constexpr int kR = 3;        // relations
constexpr int kE = 500000;   // edges per relation
constexpr int kB = 2;        // bases
constexpr int kRN = kR * kN;              // 300000 segments
constexpr int kRE = kR * kE;              // 1500000 edges
constexpr int kKS = kR * kD;              // stacked K = 384
constexpr int kKC = kD + kKS;             // fused K = 512
constexpr int kNBK = (kN + 511) / 512;    // node buckets per relation (196)
constexpr int kNQ = kR * kNBK;            // relation-buckets (588)
constexpr int kCB = (kRE + 2047) / 2048;  // edge-chunk blocks (733)
constexpr int kBCAP = 4096;               // bucket slot capacity (mean 2560, sigma 51 -> 30 sigma)
}

__device__ __forceinline__ ushort f2bf(float f) {
    uint u = __builtin_bit_cast(uint, f);
    u += 0x7fff + ((u >> 16) & 1);           // RNE
    return (ushort)(u >> 16);
}
__device__ __forceinline__ float bf2f(ushort h) {
    return __builtin_bit_cast(float, (uint)h << 16);
}
__device__ __forceinline__ int rel_of(int i) {
    return (i >= kE) + (i >= 2 * kE);
}

// ---------------- init: bucket cursors at fixed slot bases ----------------
__global__ __launch_bounds__(256)
void init_kernel(unsigned* __restrict__ bcur)
{
    const int q = blockIdx.x * 256 + threadIdx.x;
    if (q < kNQ) bcur[q] = (unsigned)q * kBCAP;
}

// ---------------- passB: bin edges into fixed bucket slots ----------------
// record = (src << 9) | (dst & 511); bucket q = r*kNBK + (dst>>9)
__global__ __launch_bounds__(256)
void passB_kernel(const int* __restrict__ src, const int* __restrict__ dst,
                  unsigned* __restrict__ bcur, uint* __restrict__ colbkt)
{
    __shared__ unsigned bl[kNQ];     // local counts, then local cursors
    __shared__ unsigned base_l[kNQ];
    const int tid = threadIdx.x;
    for (int q = tid; q < kNQ; q += 256) bl[q] = 0;
    __syncthreads();
    const int i0 = blockIdx.x * 2048 + tid * 8;
    int dd[8], qq[8];
    const bool full = (i0 + 8 <= kRE);
    if (full) {
        const int4 d0 = *(const int4*)(dst + i0);
        const int4 d1 = *(const int4*)(dst + i0 + 4);
        dd[0]=d0.x; dd[1]=d0.y; dd[2]=d0.z; dd[3]=d0.w;
        dd[4]=d1.x; dd[5]=d1.y; dd[6]=d1.z; dd[7]=d1.w;
        #pragma unroll
        for (int j = 0; j < 8; ++j) {
            qq[j] = rel_of(i0 + j) * kNBK + (dd[j] >> 9);
            atomicAdd(&bl[qq[j]], 1u);
        }
    } else {
        for (int j = 0; j < 8; ++j) {
            const int i = i0 + j;
            qq[j] = -1;
            if (i < kRE) {
                dd[j] = dst[i];
                qq[j] = rel_of(i) * kNBK + (dd[j] >> 9);
                atomicAdd(&bl[qq[j]], 1u);
            }
        }
    }
    __syncthreads();
    for (int q = tid; q < kNQ; q += 256) {
        const unsigned c = bl[q];
        base_l[q] = c ? atomicAdd(&bcur[q], c) : 0u;
        bl[q] = 0;   // reuse as local cursor
    }
    __syncthreads();
    if (full) {
        const int4 s0 = *(const int4*)(src + i0);
        const int4 s1 = *(const int4*)(src + i0 + 4);
        const int ss[8] = {s0.x, s0.y, s0.z, s0.w, s1.x, s1.y, s1.z, s1.w};
        #pragma unroll
        for (int j = 0; j < 8; ++j) {
            const unsigned pos = base_l[qq[j]] + atomicAdd(&bl[qq[j]], 1u);
            colbkt[pos] = ((uint)ss[j] << 9) | (uint)(dd[j] & 511);
        }
    } else {
        for (int j = 0; j < 8; ++j) {
            if (qq[j] >= 0) {
                const unsigned pos = base_l[qq[j]] + atomicAdd(&bl[qq[j]], 1u);
                colbkt[pos] = ((uint)src[i0 + j] << 9) | (uint)(dd[j] & 511);
            }
        }
    }
}

// ---------------- passC: per-bucket degree count + LDS scan -> rowseg/invd, scatter colidx ----------------
__global__ __launch_bounds__(256)
void passC_kernel(const uint* __restrict__ colbkt, const unsigned* __restrict__ bcur,
                  uint2* __restrict__ rowseg, float* __restrict__ invd,
                  int* __restrict__ colidx)
{
    __shared__ unsigned cnt[512];
    __shared__ unsigned pos[512];
    __shared__ unsigned psc[256];
    const int tid = threadIdx.x;
    const int q = blockIdx.x;            // 0..kNQ-1
    const int r = q / kNBK;
    const int b = q - r * kNBK;
    const int n0 = b << 9;
    const int nn = min(512, kN - n0);
    cnt[tid] = 0; cnt[tid + 256] = 0;
    __syncthreads();
    const unsigned e0 = (unsigned)q * kBCAP;
    const unsigned e1 = bcur[q];
    for (unsigned j = e0 + tid; j < e1; j += 256)
        atomicAdd(&cnt[colbkt[j] & 511u], 1u);
    __syncthreads();
    // exclusive scan of 512 counts (pairwise + Hillis-Steele over 256)
    const unsigned c0 = cnt[2 * tid], c1 = cnt[2 * tid + 1];
    const unsigned psum = c0 + c1;
    psc[tid] = psum;
    __syncthreads();
    #pragma unroll
    for (int off = 1; off < 256; off <<= 1) {
        unsigned t = (tid >= off) ? psc[tid - off] : 0u;
        __syncthreads();
        psc[tid] += t;
        __syncthreads();
    }
    const unsigned pex = psc[tid] - psum;      // exclusive prefix of pair
    const unsigned ex0 = e0 + pex;             // absolute colidx slot of node 2*tid
    const unsigned ex1 = ex0 + c0;
    pos[2 * tid] = ex0;
    pos[2 * tid + 1] = ex1;
    // emit rowseg + invd for the two nodes this thread owns
    const int g0 = 2 * tid, g1 = 2 * tid + 1;
    if (g0 < nn) {
        rowseg[(size_t)r * kN + n0 + g0] = make_uint2(ex0, ex0 + c0);
        invd[(size_t)r * kN + n0 + g0] = 1.0f / (float)(c0 > 1u ? c0 : 1u);
    }
    if (g1 < nn) {
        rowseg[(size_t)r * kN + n0 + g1] = make_uint2(ex1, ex1 + c1);
        invd[(size_t)r * kN + n0 + g1] = 1.0f / (float)(c1 > 1u ? c1 : 1u);
    }
    __syncthreads();
    // scatter into slotted colidx
    for (unsigned j = e0 + tid; j < e1; j += 256) {
        const uint p = colbkt[j];
        const unsigned pp = atomicAdd(&pos[p & 511u], 1u);
        colidx[pp] = (int)(p >> 9);
    }
}

// ---------------- fused weight prep ----------------
// blocks [0,64): WTp = proj_w^T (bf16); [64,320): WTc1; [320,576): WTc2
__device__ __forceinline__ void wcomb_one(int i, const float* loopW, const float* basis,
                                          const float* coeff, ushort* WTc)
{
    int out = i >> 9;
    int k = i & (kKC - 1);
    float v;
    if (k < kD) {
        v = loopW[(size_t)k * kD + out];
    } else {
        int j = k - kD;
        int r = j >> 7, d = j & 127;
        v = coeff[r * kB] * basis[(size_t)d * kD + out]
          + coeff[r * kB + 1] * basis[(size_t)kD * kD + d * kD + out];
    }
    WTc[i] = f2bf(v);
}

__global__ __launch_bounds__(256)
void prep_kernel(const float* __restrict__ proj_w,
                 const float* __restrict__ loop1, const float* __restrict__ basis1,
                 const float* __restrict__ coeff1,
                 const float* __restrict__ loop2, const float* __restrict__ basis2,
                 const float* __restrict__ coeff2,
                 ushort* __restrict__ WTp, ushort* __restrict__ WTc1,
                 ushort* __restrict__ WTc2)
{
    const int b = blockIdx.x;
    const int tid = threadIdx.x;
    if (b < 64) {
        const int i = b * 256 + tid;           // 16384
        const int out = i >> 7, k = i & 127;
        WTp[i] = f2bf(proj_w[(size_t)k * kD + out]);
    } else if (b < 320) {
        wcomb_one((b - 64) * 256 + tid, loop1, basis1, coeff1, WTc1);
    } else {
        wcomb_one((b - 320) * 256 + tid, loop2, basis2, coeff2, WTc2);
    }
}

// ---------------- gather: a[n, r*128+c] = invdeg[r,n] * sum in[src, c] ----------------
// 8-lane groups, one segment per group (32 segs/block); 32B/lane; 2 rows in flight/group.
__device__ __forceinline__ void acc8(float* s, uint4 v) {
    s[0] += bf2f((ushort)(v.x & 0xffffu)); s[1] += bf2f((ushort)(v.x >> 16));
    s[2] += bf2f((ushort)(v.y & 0xffffu)); s[3] += bf2f((ushort)(v.y >> 16));
    s[4] += bf2f((ushort)(v.z & 0xffffu)); s[5] += bf2f((ushort)(v.z >> 16));
    s[6] += bf2f((ushort)(v.w & 0xffffu)); s[7] += bf2f((ushort)(v.w >> 16));
}

__global__ __launch_bounds__(256)
void gather_kernel(const ushort* __restrict__ in, const uint2* __restrict__ rowseg,
                   const int* __restrict__ colidx, const float* __restrict__ invd,
                   ushort* __restrict__ a)
{
    const int tid = threadIdx.x;
    const int g   = tid >> 3;            // 0..31: segment slot
    const int c   = tid & 7;             // 32B column chunk (16 bf16)
    const int seg = blockIdx.x * 32 + g; // grid exact: 9375*32 = 300000
    const int r = seg / kN;
    const int n = seg - r * kN;
    const uint2 be = rowseg[seg];
    const unsigned end = be.y;

    float s[16];
    #pragma unroll
    for (int i = 0; i < 16; ++i) s[i] = 0.f;

    unsigned j = be.x;
    for (; j + 1 < end; j += 2) {
        const int ea = colidx[j];
        const int eb = colidx[j + 1];
        const ushort* pa = in + (size_t)ea * kD + c * 16;
        const ushort* pb = in + (size_t)eb * kD + c * 16;
        const uint4 va0 = *(const uint4*)pa;
        const uint4 va1 = *(const uint4*)(pa + 8);
        const uint4 vb0 = *(const uint4*)pb;
        const uint4 vb1 = *(const uint4*)(pb + 8);
        acc8(s, va0); acc8(s + 8, va1);
        acc8(s, vb0); acc8(s + 8, vb1);
    }
    if (j < end) {
        const int ea = colidx[j];
        const ushort* pa = in + (size_t)ea * kD + c * 16;
        const uint4 va0 = *(const uint4*)pa;
        const uint4 va1 = *(const uint4*)(pa + 8);
        acc8(s, va0); acc8(s + 8, va1);
    }

    const float w = invd[seg];
    uint4 o0, o1;
    o0.x = (uint)f2bf(s[0] * w)  | ((uint)f2bf(s[1] * w)  << 16);
    o0.y = (uint)f2bf(s[2] * w)  | ((uint)f2bf(s[3] * w)  << 16);
    o0.z = (uint)f2bf(s[4] * w)  | ((uint)f2bf(s[5] * w)  << 16);
    o0.w = (uint)f2bf(s[6] * w)  | ((uint)f2bf(s[7] * w)  << 16);
    o1.x = (uint)f2bf(s[8] * w)  | ((uint)f2bf(s[9] * w)  << 16);
    o1.y = (uint)f2bf(s[10] * w) | ((uint)f2bf(s[11] * w) << 16);
    o1.z = (uint)f2bf(s[12] * w) | ((uint)f2bf(s[13] * w) << 16);
    o1.w = (uint)f2bf(s[14] * w) | ((uint)f2bf(s[15] * w) << 16);
    ushort* ap = a + (size_t)n * kKS + r * kD + c * 16;
    *(uint4*)ap       = o0;
    *(uint4*)(ap + 8) = o1;
}

// ---------------- MFMA GEMM: C[M,128] = [A0 | A1][M,NT*64] @ WT^T (+bias) ----------------
// A0: first NT0 64-chunks (fp32 if AFP32, else bf16; row stride NT0*64);
// A1: remaining chunks (bf16, row stride (NT-NT0)*64).
// WT: [128][NT*64] pre-transposed bf16. 256 thr, 4 waves 2x2 of 64x64.
// LDS tiles [128][64] bf16, XOR-swizzled (16B chunk index ^= row&7), linear ds_write.
template<int NT0, int NT, bool AFP32, bool RELUOUT, bool OUTBF16>
__global__ __launch_bounds__(256)
void mfma_gemm(const void* __restrict__ A0, const ushort* __restrict__ A1,
               const ushort* __restrict__ WT, const float* __restrict__ bias,
               void* __restrict__ Cout, int M)
{
    __shared__ ushort As[128 * 64];
    __shared__ ushort Bs[128 * 64];
    const int tid  = threadIdx.x;
    const int bm   = blockIdx.x * 128;
    const int lane = tid & 63;
    const int w    = tid >> 6;
    const int wrow = (w >> 1) * 64;
    const int wcol = (w & 1) * 64;

    f32x4 acc[4][4];
    #pragma unroll
    for (int i = 0; i < 4; ++i)
        #pragma unroll
        for (int j = 0; j < 4; ++j)
            acc[i][j] = (f32x4){0.f, 0.f, 0.f, 0.f};

    uint4 a4[4], b4[4];
    int arowL[4], osrcL[4];
    #pragma unroll
    for (int st = 0; st < 4; ++st) {
        const int m = st * 256 + tid;
        const int row = m >> 3;
        arowL[st] = row;
        osrcL[st] = (m & 7) ^ (row & 7);
    }

    auto load_tile = [&](int kt) {
        #pragma unroll
        for (int st = 0; st < 4; ++st) {
            const int row = arowL[st];
            const int osrc = osrcL[st];
            int arow = bm + row; if (arow >= M) arow = M - 1;   // clamp: rows>=M unused
            if (kt < NT0) {
                if (AFP32) {
                    const float* ap = (const float*)A0 + (size_t)arow * (NT0 * 64) + kt * 64 + osrc * 8;
                    const float4 f0 = *(const float4*)ap;
                    const float4 f1 = *(const float4*)(ap + 4);
                    a4[st].x = (uint)f2bf(f0.x) | ((uint)f2bf(f0.y) << 16);
                    a4[st].y = (uint)f2bf(f0.z) | ((uint)f2bf(f0.w) << 16);
                    a4[st].z = (uint)f2bf(f1.x) | ((uint)f2bf(f1.y) << 16);
                    a4[st].w = (uint)f2bf(f1.z) | ((uint)f2bf(f1.w) << 16);
                } else {
                    a4[st] = *(const uint4*)((const ushort*)A0 + (size_t)arow * (NT0 * 64) + kt * 64 + osrc * 8);
                }
            } else {
                a4[st] = *(const uint4*)(A1 + (size_t)arow * ((NT - NT0) * 64) + (kt - NT0) * 64 + osrc * 8);
            }
            b4[st] = *(const uint4*)(WT + (size_t)row * (NT * 64) + kt * 64 + osrc * 8);
        }
    };

    load_tile(0);
    #pragma unroll
    for (int kt = 0; kt < NT; ++kt) {
        __syncthreads();
        #pragma unroll
        for (int st = 0; st < 4; ++st) {
            const int m = st * 256 + tid;
            *(uint4*)&As[m * 8] = a4[st];
            *(uint4*)&Bs[m * 8] = b4[st];
        }
        __syncthreads();
        if (kt + 1 < NT) load_tile(kt + 1);   // prefetch under MFMA

        #pragma unroll
        for (int ks = 0; ks < 2; ++ks) {
            const int oq = ks * 4 + (lane >> 4);
            bf16x8 af[4], bfr[4];
            #pragma unroll
            for (int am = 0; am < 4; ++am) {
                const int row = wrow + am * 16 + (lane & 15);
                const int oL = oq ^ (row & 7);
                af[am] = *(const bf16x8*)&As[row * 64 + oL * 8];
            }
            #pragma unroll
            for (int bn = 0; bn < 4; ++bn) {
                const int row = wcol + bn * 16 + (lane & 15);
                const int oL = oq ^ (row & 7);
                bfr[bn] = *(const bf16x8*)&Bs[row * 64 + oL * 8];
            }
            #pragma unroll
            for (int am = 0; am < 4; ++am)
                #pragma unroll
                for (int bn = 0; bn < 4; ++bn)
                    acc[am][bn] = __builtin_amdgcn_mfma_f32_16x16x32_bf16(
                        af[am], bfr[bn], acc[am][bn], 0, 0, 0);
        }
    }

    // epilogue: row = bm+wrow+am*16+4*(lane>>4)+r ; col = wcol+bn*16+(lane&15)
    const int ccol = wcol + (lane & 15);
    float bb[4];
    #pragma unroll
    for (int bn = 0; bn < 4; ++bn) bb[bn] = bias[ccol + bn * 16];

    const int crow0 = bm + wrow + 4 * (lane >> 4);
    #pragma unroll
    for (int am = 0; am < 4; ++am) {
        #pragma unroll
        for (int r = 0; r < 4; ++r) {
            const int row = crow0 + am * 16 + r;
            if (row < M) {
                #pragma unroll
                for (int bn = 0; bn < 4; ++bn) {
                    float v = acc[am][bn][r] + bb[bn];
                    if (RELUOUT) v = fmaxf(v, 0.f);
                    if (OUTBF16)
                        ((ushort*)Cout)[(size_t)row * kD + ccol + bn * 16] = f2bf(v);
                    else
                        ((float*)Cout)[(size_t)row * kD + ccol + bn * 16] = v;
                }
            }
        }
    }
}

extern "C" void kernel_launch(void* const* d_in, const int* in_sizes, int n_in,
                              void* d_out, int out_size, void* d_ws, size_t ws_size,
                              hipStream_t stream)
{
    const float* x      = (const float*)d_in[0];
    const int*   esrc   = (const int*)d_in[1];
    const int*   edst   = (const int*)d_in[2];
    const float* proj_w = (const float*)d_in[3];
    const float* proj_b = (const float*)d_in[4];
    const float* basis1 = (const float*)d_in[5];
    const float* coeff1 = (const float*)d_in[6];
    const float* bias1  = (const float*)d_in[7];
    const float* loop1  = (const float*)d_in[8];
    const float* basis2 = (const float*)d_in[9];
    const float* coeff2 = (const float*)d_in[10];
    const float* bias2  = (const float*)d_in[11];
    const float* loop2  = (const float*)d_in[12];

    // ---- workspace layout ----
    char* p = (char*)d_ws;
    ushort* hb    = (ushort*)p;  p += (size_t)kN * kD * 2;        // bf16 h (proj out)
    ushort* r1b   = (ushort*)p;  p += (size_t)kN * kD * 2;        // bf16 relu(layer1)
    ushort* ab    = (ushort*)p;  p += (size_t)kN * kKS * 2;       // bf16 gathered [N,384]
    ushort* WTp   = (ushort*)p;  p += (size_t)kD * kD * 2;        // proj_w^T
    ushort* WTc1  = (ushort*)p;  p += (size_t)kD * kKC * 2;       // [loop1 | Wstk1]^T
    ushort* WTc2  = (ushort*)p;  p += (size_t)kD * kKC * 2;       // [loop2 | Wstk2]^T
    float* invd   = (float*)p;   p += (size_t)kRN * 4;
    uint2* rowseg = (uint2*)p;   p += (size_t)kRN * 8;
    unsigned* bcur = (unsigned*)p;  p += (size_t)kNQ * 4;
    uint* colbkt   = (uint*)p;      p += (size_t)kNQ * kBCAP * 4;
    int* colidx    = (int*)p;       p += (size_t)kNQ * kBCAP * 4;

    // ---- CSR build: fixed bucket slots, no global count/scan ----
    init_kernel<<<(kNQ + 255) / 256, 256, 0, stream>>>(bcur);
    passB_kernel<<<kCB, 256, 0, stream>>>(esrc, edst, bcur, colbkt);
    passC_kernel<<<kNQ, 256, 0, stream>>>(colbkt, bcur, rowseg, invd, colidx);

    // ---- fused weight prep ----
    prep_kernel<<<576, 256, 0, stream>>>(proj_w, loop1, basis1, coeff1,
                                         loop2, basis2, coeff2, WTp, WTc1, WTc2);

    const int gblocks = (kN + 127) / 128;   // 782
    const int gatherblocks = kRN / 32;      // 9375 exact

    // ---- projection: hb = bf16(x @ proj_w + proj_b), fp32 A read in-GEMM ----
    mfma_gemm<2, 2, true, false, true><<<gblocks, 256, 0, stream>>>(
        x, nullptr, WTp, proj_b, hb, kN);

    // ---- layer 1: r1b = bf16(relu([h | gather(h)] @ [loop1|Wstk1] + bias1)) ----
    gather_kernel<<<gatherblocks, 256, 0, stream>>>(hb, rowseg, colidx, invd, ab);
    mfma_gemm<2, 8, false, true, true><<<gblocks, 256, 0, stream>>>(
        hb, ab, WTc1, bias1, r1b, kN);

    // ---- layer 2: out = relu([r1 | gather(r1)] @ [loop2|Wstk2] + bias2) (fp32) ----
    gather_kernel<<<gatherblocks, 256, 0, stream>>>(r1b, rowseg, colidx, invd, ab);
    mfma_gemm<2, 8, false, true, false><<<gblocks, 256, 0, stream>>>(
        r1b, ab, WTc2, bias2, d_out, kN);
}